// Round 1
// baseline (243.604 us; speedup 1.0000x reference)
//
#include <hip/hip_runtime.h>

// SelfAttention (B=4, C=256, H=W=64): fused projections + split-K flash attention.
// Round 4: r3 measured k_flash=116us with MfmaUtil 16%, VALUBusy 23%, HBM 3.7%,
// occupancy 42% -> latency/barrier-bound, not any pipe. This round removes the
// exposed per-iteration staging latency:
//  - V is wave-private (wave w owns rows [32w,32w+32), exactly what its PV
//    fragments read): register-prefetched one tile ahead, ds_write after PV,
//    no barrier ever needed for V (same-wave DS ops are in-order).
//  - K and Q fragments load directly global->VGPR (L2-resident), K prefetched
//    one iteration ahead. K LDS staging + Q staging + 2 prologue barriers gone.
//  - Raw s_barrier + manual lgkmcnt(0) instead of __syncthreads so the
//    in-flight K/V prefetch loads are NOT vmcnt-drained at barriers.
//  - s_setprio(1) around MFMA clusters.

#define B_ 4
#define C_ 256
#define N_ 4096
#define CQK 32

typedef __attribute__((ext_vector_type(8))) short short8;
typedef __attribute__((ext_vector_type(4))) short short4v;
typedef __attribute__((ext_vector_type(16))) float f32x16;
typedef __attribute__((ext_vector_type(4))) float f32x4;

__device__ __forceinline__ unsigned short f2bf(float f) {
  unsigned int u = __builtin_bit_cast(unsigned int, f);
  u = (u + 0x7fffu + ((u >> 16) & 1u)) >> 16;  // RNE
  return (unsigned short)u;
}
__device__ __forceinline__ float bf2f(unsigned short s) {
  unsigned int u = ((unsigned int)s) << 16;
  return __builtin_bit_cast(float, u);
}
__device__ __forceinline__ f32x16 mfma16(short8 a, short8 b, f32x16 c) {
  return __builtin_amdgcn_mfma_f32_32x32x16_bf16(a, b, c, 0, 0, 0);
}
// swizzled element index into bf16 LDS tiles (16B granules XORed by row)
__device__ __forceinline__ int swz64(int row, int col) {  // rows of 64 bf16
  return row * 64 + ((((col >> 3) ^ row) & 7) << 3) + (col & 7);
}

// write-visibility barrier: drain LDS ops, leave global loads in flight
#define BAR_SYNC                                        \
  do {                                                  \
    asm volatile("s_waitcnt lgkmcnt(0)" ::: "memory");  \
    __builtin_amdgcn_s_barrier();                       \
  } while (0)
// execution-only barrier (no waitcnt: ordered data already consumed into regs)
#define BAR_FAST __builtin_amdgcn_s_barrier()

// ---------------- kernel 1: prep (x transpose+split, weight splits) ----------
// blocks [0,1024): x [B][C][N] fp32 -> xthi/xtlo [B][N][C] bf16 (64x64 tiles)
// blocks [1024,1344): hi/lo split of Wq|Wk|Wv (81920 elems)
__global__ __launch_bounds__(256) void k_prep(
    const float* __restrict__ x, unsigned short* __restrict__ xthi,
    unsigned short* __restrict__ xtlo,
    const float* __restrict__ Wq, const float* __restrict__ Wk,
    const float* __restrict__ Wv,
    unsigned short* __restrict__ wqh, unsigned short* __restrict__ wql,
    unsigned short* __restrict__ wkh, unsigned short* __restrict__ wkl,
    unsigned short* __restrict__ wvh, unsigned short* __restrict__ wvl) {
  __shared__ __align__(16) float tile[64 * 65];
  const int bi = blockIdx.x;
  const int t = threadIdx.x;
  if (bi < 1024) {
    const int it = bi & 63, ct = (bi >> 6) & 3, b = bi >> 8;
    const int i0 = it * 64, c0 = ct * 64;
    {
      const int i = t & 63, cb = t >> 6;
#pragma unroll
      for (int z = 0; z < 16; ++z) {
        const int c = z * 4 + cb;
        tile[i * 65 + c] = x[(b * C_ + c0 + c) * N_ + i0 + i];
      }
    }
    __syncthreads();
    {
      const int ii = t >> 2, p = t & 3;
      short8 h0, h1, l0, l1;
#pragma unroll
      for (int e = 0; e < 16; ++e) {
        const float f = tile[ii * 65 + p * 16 + e];
        const unsigned short hb = f2bf(f);
        const unsigned short lb = f2bf(f - bf2f(hb));
        if (e < 8) { h0[e] = (short)hb; l0[e] = (short)lb; }
        else       { h1[e - 8] = (short)hb; l1[e - 8] = (short)lb; }
      }
      const int base = (b * N_ + i0 + ii) * C_ + c0 + p * 16;
      *(short8*)(xthi + base) = h0;
      *(short8*)(xthi + base + 8) = h1;
      *(short8*)(xtlo + base) = l0;
      *(short8*)(xtlo + base + 8) = l1;
    }
  } else {
    const int e = (bi - 1024) * 256 + t;  // < 81920
    const float* src; unsigned short *hi, *lo; int idx;
    if (e < 8192)        { src = Wq; hi = wqh; lo = wql; idx = e; }
    else if (e < 16384)  { src = Wk; hi = wkh; lo = wkl; idx = e - 8192; }
    else                 { src = Wv; hi = wvh; lo = wvl; idx = e - 16384; }
    const float f = src[idx];
    const unsigned short h = f2bf(f);
    hi[idx] = h;
    lo[idx] = f2bf(f - bf2f(h));
  }
}

// ---------------- kernel 2: fused q/k/v projection GEMM ----------------
// C[o][i] = sum_c W[o][c] * x[c][i] + bias, o in [0,320) concat(q32,k32,v256)
// q,k written transposed: [B][N][32] hi/lo bf16; v written [B][C][N] bf16.
__global__ __launch_bounds__(256) void k_proj(
    const unsigned short* __restrict__ wqh, const unsigned short* __restrict__ wql,
    const unsigned short* __restrict__ wkh, const unsigned short* __restrict__ wkl,
    const unsigned short* __restrict__ wvh, const unsigned short* __restrict__ wvl,
    const unsigned short* __restrict__ xthi, const unsigned short* __restrict__ xtlo,
    const float* __restrict__ bq, const float* __restrict__ bk,
    const float* __restrict__ bv,
    unsigned short* __restrict__ qhg, unsigned short* __restrict__ qlg,
    unsigned short* __restrict__ khg, unsigned short* __restrict__ klg,
    unsigned short* __restrict__ vg) {
  __shared__ __align__(16) char sm[33792];
  unsigned short* awh = (unsigned short*)sm;       // [64][64] W hi (swizzled)
  unsigned short* awl = awh + 4096;
  unsigned short* bxh = awl + 4096;                // [64][64] x^T hi
  unsigned short* bxl = bxh + 4096;
  float* qt = (float*)sm;                          // epilogue reuse: [64][65] f32

  const int it = blockIdx.x, ot = blockIdx.y, b = blockIdx.z;
  const int i0 = it * 64, o0 = ot * 64;
  const int t = threadIdx.x, lane = t & 63, w = t >> 6, h = lane >> 5;
  const int mb = w >> 1, nb = w & 1;
  const int srow = t >> 2, sp = t & 3;

  const int og = o0 + srow;
  const unsigned short *wh, *wl;
  if (og < 32)      { wh = wqh + og * C_;        wl = wql + og * C_; }
  else if (og < 64) { wh = wkh + (og - 32) * C_; wl = wkl + (og - 32) * C_; }
  else              { wh = wvh + (og - 64) * C_; wl = wvl + (og - 64) * C_; }
  const unsigned short* xh = xthi + (b * N_ + i0 + srow) * C_;
  const unsigned short* xl = xtlo + (b * N_ + i0 + srow) * C_;

  f32x16 acc;
#pragma unroll
  for (int e = 0; e < 16; ++e) acc[e] = 0.f;
  const int m = 32 * mb + (lane & 31);
  const int n = 32 * nb + (lane & 31);

  for (int kt = 0; kt < 4; ++kt) {
    const int cb = kt * 64 + sp * 16;
    *(short8*)&awh[swz64(srow, sp * 16)]     = *(const short8*)(wh + cb);
    *(short8*)&awh[swz64(srow, sp * 16 + 8)] = *(const short8*)(wh + cb + 8);
    *(short8*)&awl[swz64(srow, sp * 16)]     = *(const short8*)(wl + cb);
    *(short8*)&awl[swz64(srow, sp * 16 + 8)] = *(const short8*)(wl + cb + 8);
    *(short8*)&bxh[swz64(srow, sp * 16)]     = *(const short8*)(xh + cb);
    *(short8*)&bxh[swz64(srow, sp * 16 + 8)] = *(const short8*)(xh + cb + 8);
    *(short8*)&bxl[swz64(srow, sp * 16)]     = *(const short8*)(xl + cb);
    *(short8*)&bxl[swz64(srow, sp * 16 + 8)] = *(const short8*)(xl + cb + 8);
    __syncthreads();
#pragma unroll
    for (int kk = 0; kk < 4; ++kk) {
      const int kb = kk * 16 + h * 8;
      const short8 ah  = *(const short8*)&awh[swz64(m, kb)];
      const short8 al2 = *(const short8*)&awl[swz64(m, kb)];
      const short8 bh  = *(const short8*)&bxh[swz64(n, kb)];
      const short8 bl2 = *(const short8*)&bxl[swz64(n, kb)];
      acc = mfma16(ah, bh, acc);   // hi*hi
      acc = mfma16(ah, bl2, acc);  // hi*lo
      acc = mfma16(al2, bh, acc);  // lo*hi
    }
    __syncthreads();
  }

  if (ot > 0) {  // v epilogue: direct [B][C][N] bf16 store
#pragma unroll
    for (int e = 0; e < 16; ++e) {
      const int r = 32 * mb + (e & 3) + 8 * (e >> 2) + 4 * h;
      const int oc = o0 - 64 + r;
      vg[(b * C_ + oc) * N_ + i0 + n] = f2bf(acc[e] + bv[oc]);
    }
  } else {  // q/k epilogue: LDS transpose -> [B][N][32] hi/lo
#pragma unroll
    for (int e = 0; e < 16; ++e) {
      const int r = 32 * mb + (e & 3) + 8 * (e >> 2) + 4 * h;
      const float bias = (r < 32) ? bq[r] : bk[r - 32];
      qt[r * 65 + n] = acc[e] + bias;
    }
    __syncthreads();
    const int ii = t >> 2;
    short8 hv0, hv1, lv0, lv1;
#pragma unroll
    for (int e = 0; e < 16; ++e) {
      const float f = qt[(sp * 16 + e) * 65 + ii];
      const unsigned short hb = f2bf(f);
      const unsigned short lb = f2bf(f - bf2f(hb));
      if (e < 8) { hv0[e] = (short)hb; lv0[e] = (short)lb; }
      else       { hv1[e - 8] = (short)hb; lv1[e - 8] = (short)lb; }
    }
    if (sp < 2) {
      const int base = (b * N_ + i0 + ii) * CQK + sp * 16;
      *(short8*)(qhg + base) = hv0; *(short8*)(qhg + base + 8) = hv1;
      *(short8*)(qlg + base) = lv0; *(short8*)(qlg + base + 8) = lv1;
    } else {
      const int base = (b * N_ + i0 + ii) * CQK + sp * 16 - 32;
      *(short8*)(khg + base) = hv0; *(short8*)(khg + base + 8) = hv1;
      *(short8*)(klg + base) = lv0; *(short8*)(klg + base + 8) = lv1;
    }
  }
}

// ---------------- kernel 3: split-K flash attention ----------------
// 512 blocks: blk = (qt<<3)|(b<<1)|half. Each block: Qtile=64, keys
// [half*2048, half*2048+2048) in 32 iters of 64. Writes unnormalized O (f16,
// [c][i] layout) + per-row (m,l) stats for the combine kernel.
// LDS: stf [64][64] f32 (S; P bf16 aliases) | vt [256][64] bf16 (wave-private
// 32-row slices) | alphaf[64]. Epilogue reuses the full 64KB as otf.
__global__ __launch_bounds__(512, 4) void k_flash(
    const unsigned short* __restrict__ qhg, const unsigned short* __restrict__ qlg,
    const unsigned short* __restrict__ khg, const unsigned short* __restrict__ klg,
    const unsigned short* __restrict__ vg,
    unsigned short* __restrict__ Opart, float* __restrict__ mlpart) {
  __shared__ __align__(16) char sm[65536];
  float* stf = (float*)sm;                             // [64][64] f32 S, swizzled
  char* stb = sm;                                      // P (bf16) aliases stf
  unsigned short* vt = (unsigned short*)(sm + 16384);  // [256][64] bf16
  float* alphaf = (float*)(sm + 49152);                // [64]
  float* otf = (float*)sm;                             // epilogue [256][64] f32

  // XCD-aware: blk%8 = XCD -> fixed (b,half) per XCD; per-XCD K/V ~1.3MB < L2.
  const int blk = blockIdx.x;
  const int b = (blk >> 1) & 3;
  const int half = blk & 1;
  const int qt_ = blk >> 3;
  const int q0 = qt_ * 64;
  const int jbase = half * 2048;
  const int t = threadIdx.x, lane = t & 63, w = t >> 6, h = lane >> 5;
  const int l31 = lane & 31;
  const int r_sm = t >> 3, p_sm = t & 7;
  const int mbs = (w >> 1) & 1, nbs = w & 1;

  // ---- wave-private V slice: wave w owns rows [32w, 32w+32) ----
  // load pass p: row = 32w + 8p + (lane>>3), cols [(lane&7)*8, +8) -> each pass
  // reads 8 rows x 128B contiguous (coalesced); PV reads only these rows.
  const int vrow = 32 * w + (lane >> 3);
  const int vcol = (lane & 7) * 8;
  const unsigned short* vsrc =
      vg + (size_t)(b * C_ + vrow) * N_ + jbase + vcol;

  // issue V(0)
  short8 vst[4];
#pragma unroll
  for (int p = 0; p < 4; ++p)
    vst[p] = *(const short8*)(vsrc + p * 8 * N_);

  // Q fragments + K(0) straight from global (L2-resident), waves 0..3 only
  short8 qfh[2], qfl[2], kfh[2], kfl[2];
  const unsigned short* qph =
      qhg + (size_t)(b * N_ + q0 + 32 * mbs + l31) * CQK + h * 8;
  const unsigned short* qpl =
      qlg + (size_t)(b * N_ + q0 + 32 * mbs + l31) * CQK + h * 8;
  const unsigned short* kph =
      khg + (size_t)(b * N_ + jbase + 32 * nbs + l31) * CQK + h * 8;
  const unsigned short* kpl =
      klg + (size_t)(b * N_ + jbase + 32 * nbs + l31) * CQK + h * 8;
  if (w < 4) {
#pragma unroll
    for (int kk = 0; kk < 2; ++kk) {
      qfh[kk] = *(const short8*)(qph + kk * 16);
      qfl[kk] = *(const short8*)(qpl + kk * 16);
      kfh[kk] = *(const short8*)(kph + kk * 16);
      kfl[kk] = *(const short8*)(kpl + kk * 16);
    }
  }
  // commit V(0) to LDS (wave-private, no barrier), issue V(1)
#pragma unroll
  for (int p = 0; p < 4; ++p)
    *(short8*)&vt[swz64(vrow + 8 * p, vcol)] = vst[p];
#pragma unroll
  for (int p = 0; p < 4; ++p)
    vst[p] = *(const short8*)(vsrc + 64 + p * 8 * N_);

  f32x16 acc0, acc1;
#pragma unroll
  for (int e = 0; e < 16; ++e) { acc0[e] = 0.f; acc1[e] = 0.f; }
  float m_run = -1e30f, l_run = 0.f;

  for (int kt = 0; kt < 32; ++kt) {
    BAR_FAST;  // B1: prev PV's P-reads consumed into regs -> stf writable
    if (w < 4) {
      f32x16 sa;
#pragma unroll
      for (int e = 0; e < 16; ++e) sa[e] = 0.f;
      __builtin_amdgcn_s_setprio(1);
#pragma unroll
      for (int kk = 0; kk < 2; ++kk) {
        sa = mfma16(qfh[kk], kfh[kk], sa);  // hi*hi
        sa = mfma16(qfh[kk], kfl[kk], sa);  // hi*lo
        sa = mfma16(qfl[kk], kfh[kk], sa);  // lo*hi
      }
      __builtin_amdgcn_s_setprio(0);
      const int jn = 32 * nbs + l31;
#pragma unroll
      for (int e = 0; e < 16; ++e) {
        const int ri = 32 * mbs + (e & 3) + 8 * (e >> 2) + 4 * h;
        stf[ri * 64 + ((((jn >> 2) ^ ri) & 15) << 2) + (jn & 3)] = sa[e];
      }
      // prefetch K(kt+1) into regs; consumed after next B1 (counted vmcnt)
      const int ko = ((kt + 1 < 32) ? (kt + 1) : 31) * 64 * CQK;
#pragma unroll
      for (int kk = 0; kk < 2; ++kk) {
        kfh[kk] = *(const short8*)(kph + ko + kk * 16);
        kfl[kk] = *(const short8*)(kpl + ko + kk * 16);
      }
    }
    BAR_SYNC;  // B2: S visible to all
    // online softmax: thread (r_sm,p_sm) owns cols [8p,8p+8) of row r_sm
    {
      float* p0 = stf + r_sm * 64 + ((((2 * p_sm) ^ r_sm) & 15) << 2);
      float* p1 = stf + r_sm * 64 + ((((2 * p_sm + 1) ^ r_sm) & 15) << 2);
      const f32x4 a0 = *(const f32x4*)p0;
      const f32x4 a1 = *(const f32x4*)p1;
      float s[8];
#pragma unroll
      for (int e = 0; e < 4; ++e) { s[e] = a0[e]; s[4 + e] = a1[e]; }
      float mx = s[0];
#pragma unroll
      for (int e = 1; e < 8; ++e) mx = fmaxf(mx, s[e]);
      mx = fmaxf(mx, __shfl_xor(mx, 1));
      mx = fmaxf(mx, __shfl_xor(mx, 2));
      mx = fmaxf(mx, __shfl_xor(mx, 4));
      const float mnew = fmaxf(m_run, mx);
      const float al = __expf(m_run - mnew);
      float ts = 0.f;
      short8 pv8;
#pragma unroll
      for (int e = 0; e < 8; ++e) {
        const float pe = __expf(s[e] - mnew);
        ts += pe;
        pv8[e] = (short)f2bf(pe);
      }
      ts += __shfl_xor(ts, 1);
      ts += __shfl_xor(ts, 2);
      ts += __shfl_xor(ts, 4);
      l_run = l_run * al + ts;
      m_run = mnew;
      *(short8*)p0 = pv8;  // P (bf16) overwrites the granule this thread read
      if (p_sm == 0) alphaf[r_sm] = al;
    }
    BAR_SYNC;  // B3: P + alpha visible
    // rescale O by alpha[row]
#pragma unroll
    for (int eq = 0; eq < 4; ++eq) {
      const f32x4 av0 = *(const f32x4*)&alphaf[4 * h + 8 * eq];
      const f32x4 av1 = *(const f32x4*)&alphaf[32 + 4 * h + 8 * eq];
#pragma unroll
      for (int q = 0; q < 4; ++q) {
        acc0[4 * eq + q] *= av0[q];
        acc1[4 * eq + q] *= av1[q];
      }
    }
    // O += P * V^T (V from own wave-private slice)
    {
      const int crow = 32 * w + l31;
      __builtin_amdgcn_s_setprio(1);
#pragma unroll
      for (int kk = 0; kk < 4; ++kk) {
        const int g0 = ((4 * kk + 2 * h) ^ l31) & 15;  // P col-granule swizzle
        const short8 pa0 = *(const short8*)(stb + l31 * 256 + (g0 << 4));
        const short8 pa1 = *(const short8*)(stb + (32 + l31) * 256 + (g0 << 4));
        const short8 vf = *(const short8*)&vt[swz64(crow, kk * 16 + h * 8)];
        acc0 = mfma16(pa0, vf, acc0);
        acc1 = mfma16(pa1, vf, acc1);
      }
      __builtin_amdgcn_s_setprio(0);
    }
    // commit V(kt+1) (wave-private; same-wave DS ops are in-order vs the PV
    // reads above), then issue V(kt+2) -> ~1 full iteration in flight
#pragma unroll
    for (int p = 0; p < 4; ++p)
      *(short8*)&vt[swz64(vrow + 8 * p, vcol)] = vst[p];
    const int vo = ((kt + 2 < 32) ? (kt + 2) : 31) * 64;
#pragma unroll
    for (int p = 0; p < 4; ++p)
      vst[p] = *(const short8*)(vsrc + vo + p * 8 * N_);
  }

  // write per-row stats (m,l); O stays unnormalized (combine divides)
  if (p_sm == 0) {
    mlpart[blk * 128 + r_sm] = m_run;
    mlpart[blk * 128 + 64 + r_sm] = l_run;
  }
  BAR_FAST;  // last PV reads consumed -> stf/vt reusable as otf
  // transpose O through LDS, store f16 partials [c][i]
  {
    const int cc = 32 * w + l31;
#pragma unroll
    for (int e = 0; e < 16; ++e) {
      const int r0 = (e & 3) + 8 * (e >> 2) + 4 * h;
      otf[cc * 64 + ((((r0 >> 2) ^ cc) & 15) << 2) + (r0 & 3)] = acc0[e];
      const int r1 = 32 + r0;
      otf[cc * 64 + ((((r1 >> 2) ^ cc) & 15) << 2) + (r1 & 3)] = acc1[e];
    }
  }
  BAR_SYNC;  // otf visible cross-wave
#pragma unroll
  for (int pass = 0; pass < 8; ++pass) {
    const int idx = pass * 512 + t;
    const int c = idx >> 4, gi = idx & 15;
    const f32x4 ov = *(const f32x4*)(otf + c * 64 + (((gi ^ c) & 15) << 2));
    short4v hv;
#pragma unroll
    for (int q = 0; q < 4; ++q) {
      const _Float16 hf = (_Float16)ov[q];
      hv[q] = __builtin_bit_cast(short, hf);
    }
    *(short4v*)(Opart + blk * 16384 + c * 64 + gi * 4) = hv;
  }
}

// ---------------- kernel 4: combine halves + residual ----------------
// grid 256 = (b,qt). O = (w1*O1u + w2*O2u) / (w1*l1 + w2*l2); out = g*O + x.
__global__ __launch_bounds__(256) void k_combine(
    const unsigned short* __restrict__ Opart, const float* __restrict__ mlpart,
    const float* __restrict__ x, const float* __restrict__ gamma,
    float* __restrict__ out) {
  const int cb = blockIdx.x;
  const int b = cb & 3, qt_ = cb >> 2;
  const int q0 = qt_ * 64;
  const int blk1 = (qt_ << 3) | (b << 1);
  const int blk2 = blk1 | 1;
  const int t = threadIdx.x;
  const int i = t & 63, cg = t >> 6;

  const float m1 = mlpart[blk1 * 128 + i], l1 = mlpart[blk1 * 128 + 64 + i];
  const float m2 = mlpart[blk2 * 128 + i], l2 = mlpart[blk2 * 128 + 64 + i];
  const float M = fmaxf(m1, m2);
  const float w1 = __expf(m1 - M), w2 = __expf(m2 - M);
  const float inv = 1.f / (w1 * l1 + w2 * l2);
  const float gm = gamma[0];
  const float s1 = gm * w1 * inv, s2 = gm * w2 * inv;

  const unsigned short* p1 = Opart + blk1 * 16384 + i;
  const unsigned short* p2 = Opart + blk2 * 16384 + i;
#pragma unroll 4
  for (int c = cg; c < C_; c += 4) {
    const float o1 = (float)__builtin_bit_cast(_Float16, p1[c * 64]);
    const float o2 = (float)__builtin_bit_cast(_Float16, p2[c * 64]);
    const int g = (b * C_ + c) * N_ + q0 + i;
    out[g] = s1 * o1 + s2 * o2 + x[g];
  }
}

// ---------------- launch ----------------
extern "C" void kernel_launch(void* const* d_in, const int* in_sizes, int n_in,
                              void* d_out, int out_size, void* d_ws, size_t ws_size,
                              hipStream_t stream) {
  const float* x     = (const float*)d_in[0];
  const float* Wq    = (const float*)d_in[1];
  const float* bq    = (const float*)d_in[2];
  const float* Wk    = (const float*)d_in[3];
  const float* bk    = (const float*)d_in[4];
  const float* Wv    = (const float*)d_in[5];
  const float* bv    = (const float*)d_in[6];
  const float* gamma = (const float*)d_in[7];
  float* out = (float*)d_out;
  (void)in_sizes; (void)n_in; (void)out_size; (void)ws_size;

  char* ws = (char*)d_ws;
  size_t off = 0;
  auto carve = [&](size_t bytes) -> char* {
    char* p = ws + off;
    off += (bytes + 255) & ~(size_t)255;
    return p;
  };
  unsigned short* xthi = (unsigned short*)carve((size_t)B_ * N_ * C_ * 2);
  unsigned short* xtlo = (unsigned short*)carve((size_t)B_ * N_ * C_ * 2);
  unsigned short* wqh  = (unsigned short*)carve(32 * 256 * 2);
  unsigned short* wql  = (unsigned short*)carve(32 * 256 * 2);
  unsigned short* wkh  = (unsigned short*)carve(32 * 256 * 2);
  unsigned short* wkl  = (unsigned short*)carve(32 * 256 * 2);
  unsigned short* wvh  = (unsigned short*)carve(256 * 256 * 2);
  unsigned short* wvl  = (unsigned short*)carve(256 * 256 * 2);
  unsigned short* qhg  = (unsigned short*)carve((size_t)B_ * N_ * CQK * 2);
  unsigned short* qlg  = (unsigned short*)carve((size_t)B_ * N_ * CQK * 2);
  unsigned short* khg  = (unsigned short*)carve((size_t)B_ * N_ * CQK * 2);
  unsigned short* klg  = (unsigned short*)carve((size_t)B_ * N_ * CQK * 2);
  unsigned short* vg   = (unsigned short*)carve((size_t)B_ * C_ * N_ * 2);
  unsigned short* Opart = (unsigned short*)carve((size_t)512 * 16384 * 2);  // f16
  float* mlpart = (float*)carve((size_t)512 * 128 * 4);

  k_prep<<<1344, 256, 0, stream>>>(x, xthi, xtlo, Wq, Wk, Wv,
                                   wqh, wql, wkh, wkl, wvh, wvl);
  k_proj<<<dim3(64, 5, B_), 256, 0, stream>>>(wqh, wql, wkh, wkl, wvh, wvl,
                                              xthi, xtlo, bq, bk, bv,
                                              qhg, qlg, khg, klg, vg);
  k_flash<<<512, 512, 0, stream>>>(qhg, qlg, khg, klg, vg, Opart, mlpart);
  k_combine<<<256, 256, 0, stream>>>(Opart, mlpart, x, gamma, out);
}

// Round 2
// 200.199 us; speedup vs baseline: 1.2168x; 1.2168x over previous
//
#include <hip/hip_runtime.h>

// SelfAttention (B=4, C=256, H=W=64): fused projections + split-K flash attention.
// Round 5: r4 regressed (150us) from register-based prefetch -> ~25 dword/thread
// scratch spill (WRITE_SIZE 24.8->51.7MB) under the 128-reg/wave cap of
// __launch_bounds__(512,4). This round keeps r3's proven phase structure but
// does all K/V staging with __builtin_amdgcn_global_load_lds (zero VGPRs,
// async DMA) using pre-swizzled GLOBAL source addresses so the swizzled LDS
// layouts are unchanged:
//  - V: wave-private rows [32w,32w+32), DMA'd by the owning wave -> visibility
//    via that wave's own counted vmcnt, no barrier ever.
//  - K: single buffer, issued post-BAR2 (deadline next iter BAR1; window =
//    softmax+PV >> L2 latency).
//  - Barriers are raw s_barrier + lgkmcnt(0); vmcnt counted (4 at BAR1,
//    1 before PV), never drained to 0 inside the loop.

#define B_ 4
#define C_ 256
#define N_ 4096
#define CQK 32

typedef __attribute__((ext_vector_type(8))) short short8;
typedef __attribute__((ext_vector_type(4))) short short4v;
typedef __attribute__((ext_vector_type(16))) float f32x16;
typedef __attribute__((ext_vector_type(4))) float f32x4;

__device__ __forceinline__ unsigned short f2bf(float f) {
  unsigned int u = __builtin_bit_cast(unsigned int, f);
  u = (u + 0x7fffu + ((u >> 16) & 1u)) >> 16;  // RNE
  return (unsigned short)u;
}
__device__ __forceinline__ float bf2f(unsigned short s) {
  unsigned int u = ((unsigned int)s) << 16;
  return __builtin_bit_cast(float, u);
}
__device__ __forceinline__ f32x16 mfma16(short8 a, short8 b, f32x16 c) {
  return __builtin_amdgcn_mfma_f32_32x32x16_bf16(a, b, c, 0, 0, 0);
}
// swizzled element index into bf16 LDS tiles (16B granules XORed by row)
__device__ __forceinline__ int swz64(int row, int col) {  // rows of 64 bf16
  return row * 64 + ((((col >> 3) ^ row) & 7) << 3) + (col & 7);
}
__device__ __forceinline__ int swz32(int row, int col) {  // rows of 32 bf16
  return row * 32 + ((((col >> 3) ^ row) & 3) << 3) + (col & 7);
}

// async global->LDS DMA, 16B per lane; LDS dest = uniform base + lane*16
#define GL16(gp, lp)                                                     \
  __builtin_amdgcn_global_load_lds(                                      \
      (const __attribute__((address_space(1))) unsigned int*)(gp),       \
      (__attribute__((address_space(3))) unsigned int*)(lp), 16, 0, 0)

#define WAITCNT(s) asm volatile("s_waitcnt " s ::: "memory")
#define BARRIER()                         \
  do {                                    \
    __builtin_amdgcn_s_barrier();         \
    asm volatile("" ::: "memory");        \
  } while (0)

// ---------------- kernel 1: prep (x transpose+split, weight splits) ----------
__global__ __launch_bounds__(256) void k_prep(
    const float* __restrict__ x, unsigned short* __restrict__ xthi,
    unsigned short* __restrict__ xtlo,
    const float* __restrict__ Wq, const float* __restrict__ Wk,
    const float* __restrict__ Wv,
    unsigned short* __restrict__ wqh, unsigned short* __restrict__ wql,
    unsigned short* __restrict__ wkh, unsigned short* __restrict__ wkl,
    unsigned short* __restrict__ wvh, unsigned short* __restrict__ wvl) {
  __shared__ __align__(16) float tile[64 * 65];
  const int bi = blockIdx.x;
  const int t = threadIdx.x;
  if (bi < 1024) {
    const int it = bi & 63, ct = (bi >> 6) & 3, b = bi >> 8;
    const int i0 = it * 64, c0 = ct * 64;
    {
      const int i = t & 63, cb = t >> 6;
#pragma unroll
      for (int z = 0; z < 16; ++z) {
        const int c = z * 4 + cb;
        tile[i * 65 + c] = x[(b * C_ + c0 + c) * N_ + i0 + i];
      }
    }
    __syncthreads();
    {
      const int ii = t >> 2, p = t & 3;
      short8 h0, h1, l0, l1;
#pragma unroll
      for (int e = 0; e < 16; ++e) {
        const float f = tile[ii * 65 + p * 16 + e];
        const unsigned short hb = f2bf(f);
        const unsigned short lb = f2bf(f - bf2f(hb));
        if (e < 8) { h0[e] = (short)hb; l0[e] = (short)lb; }
        else       { h1[e - 8] = (short)hb; l1[e - 8] = (short)lb; }
      }
      const int base = (b * N_ + i0 + ii) * C_ + c0 + p * 16;
      *(short8*)(xthi + base) = h0;
      *(short8*)(xthi + base + 8) = h1;
      *(short8*)(xtlo + base) = l0;
      *(short8*)(xtlo + base + 8) = l1;
    }
  } else {
    const int e = (bi - 1024) * 256 + t;  // < 81920
    const float* src; unsigned short *hi, *lo; int idx;
    if (e < 8192)        { src = Wq; hi = wqh; lo = wql; idx = e; }
    else if (e < 16384)  { src = Wk; hi = wkh; lo = wkl; idx = e - 8192; }
    else                 { src = Wv; hi = wvh; lo = wvl; idx = e - 16384; }
    const float f = src[idx];
    const unsigned short h = f2bf(f);
    hi[idx] = h;
    lo[idx] = f2bf(f - bf2f(h));
  }
}

// ---------------- kernel 2: fused q/k/v projection GEMM ----------------
__global__ __launch_bounds__(256) void k_proj(
    const unsigned short* __restrict__ wqh, const unsigned short* __restrict__ wql,
    const unsigned short* __restrict__ wkh, const unsigned short* __restrict__ wkl,
    const unsigned short* __restrict__ wvh, const unsigned short* __restrict__ wvl,
    const unsigned short* __restrict__ xthi, const unsigned short* __restrict__ xtlo,
    const float* __restrict__ bq, const float* __restrict__ bk,
    const float* __restrict__ bv,
    unsigned short* __restrict__ qhg, unsigned short* __restrict__ qlg,
    unsigned short* __restrict__ khg, unsigned short* __restrict__ klg,
    unsigned short* __restrict__ vg) {
  __shared__ __align__(16) char sm[33792];
  unsigned short* awh = (unsigned short*)sm;       // [64][64] W hi (swizzled)
  unsigned short* awl = awh + 4096;
  unsigned short* bxh = awl + 4096;                // [64][64] x^T hi
  unsigned short* bxl = bxh + 4096;
  float* qt = (float*)sm;                          // epilogue reuse: [64][65] f32

  const int it = blockIdx.x, ot = blockIdx.y, b = blockIdx.z;
  const int i0 = it * 64, o0 = ot * 64;
  const int t = threadIdx.x, lane = t & 63, w = t >> 6, h = lane >> 5;
  const int mb = w >> 1, nb = w & 1;
  const int srow = t >> 2, sp = t & 3;

  const int og = o0 + srow;
  const unsigned short *wh, *wl;
  if (og < 32)      { wh = wqh + og * C_;        wl = wql + og * C_; }
  else if (og < 64) { wh = wkh + (og - 32) * C_; wl = wkl + (og - 32) * C_; }
  else              { wh = wvh + (og - 64) * C_; wl = wvl + (og - 64) * C_; }
  const unsigned short* xh = xthi + (b * N_ + i0 + srow) * C_;
  const unsigned short* xl = xtlo + (b * N_ + i0 + srow) * C_;

  f32x16 acc;
#pragma unroll
  for (int e = 0; e < 16; ++e) acc[e] = 0.f;
  const int m = 32 * mb + (lane & 31);
  const int n = 32 * nb + (lane & 31);

  for (int kt = 0; kt < 4; ++kt) {
    const int cb = kt * 64 + sp * 16;
    *(short8*)&awh[swz64(srow, sp * 16)]     = *(const short8*)(wh + cb);
    *(short8*)&awh[swz64(srow, sp * 16 + 8)] = *(const short8*)(wh + cb + 8);
    *(short8*)&awl[swz64(srow, sp * 16)]     = *(const short8*)(wl + cb);
    *(short8*)&awl[swz64(srow, sp * 16 + 8)] = *(const short8*)(wl + cb + 8);
    *(short8*)&bxh[swz64(srow, sp * 16)]     = *(const short8*)(xh + cb);
    *(short8*)&bxh[swz64(srow, sp * 16 + 8)] = *(const short8*)(xh + cb + 8);
    *(short8*)&bxl[swz64(srow, sp * 16)]     = *(const short8*)(xl + cb);
    *(short8*)&bxl[swz64(srow, sp * 16 + 8)] = *(const short8*)(xl + cb + 8);
    __syncthreads();
#pragma unroll
    for (int kk = 0; kk < 4; ++kk) {
      const int kb = kk * 16 + h * 8;
      const short8 ah  = *(const short8*)&awh[swz64(m, kb)];
      const short8 al2 = *(const short8*)&awl[swz64(m, kb)];
      const short8 bh  = *(const short8*)&bxh[swz64(n, kb)];
      const short8 bl2 = *(const short8*)&bxl[swz64(n, kb)];
      acc = mfma16(ah, bh, acc);   // hi*hi
      acc = mfma16(ah, bl2, acc);  // hi*lo
      acc = mfma16(al2, bh, acc);  // lo*hi
    }
    __syncthreads();
  }

  if (ot > 0) {  // v epilogue: direct [B][C][N] bf16 store
#pragma unroll
    for (int e = 0; e < 16; ++e) {
      const int r = 32 * mb + (e & 3) + 8 * (e >> 2) + 4 * h;
      const int oc = o0 - 64 + r;
      vg[(b * C_ + oc) * N_ + i0 + n] = f2bf(acc[e] + bv[oc]);
    }
  } else {  // q/k epilogue: LDS transpose -> [B][N][32] hi/lo
#pragma unroll
    for (int e = 0; e < 16; ++e) {
      const int r = 32 * mb + (e & 3) + 8 * (e >> 2) + 4 * h;
      const float bias = (r < 32) ? bq[r] : bk[r - 32];
      qt[r * 65 + n] = acc[e] + bias;
    }
    __syncthreads();
    const int ii = t >> 2;
    short8 hv0, hv1, lv0, lv1;
#pragma unroll
    for (int e = 0; e < 16; ++e) {
      const float f = qt[(sp * 16 + e) * 65 + ii];
      const unsigned short hb = f2bf(f);
      const unsigned short lb = f2bf(f - bf2f(hb));
      if (e < 8) { hv0[e] = (short)hb; lv0[e] = (short)lb; }
      else       { hv1[e - 8] = (short)hb; lv1[e - 8] = (short)lb; }
    }
    if (sp < 2) {
      const int base = (b * N_ + i0 + ii) * CQK + sp * 16;
      *(short8*)(qhg + base) = hv0; *(short8*)(qhg + base + 8) = hv1;
      *(short8*)(qlg + base) = lv0; *(short8*)(qlg + base + 8) = lv1;
    } else {
      const int base = (b * N_ + i0 + ii) * CQK + sp * 16 - 32;
      *(short8*)(khg + base) = hv0; *(short8*)(khg + base + 8) = hv1;
      *(short8*)(klg + base) = lv0; *(short8*)(klg + base + 8) = lv1;
    }
  }
}

// ---------------- kernel 3: split-K flash attention ----------------
// 512 blocks: blk = (qt<<3)|(b<<1)|half. Per-iter barriers: BAR1 (vmcnt(4)
// lgkm: K landed, P consumed) -> S mfma -> BAR2 (lgkm: S visible) -> issue
// K(kt+1) DMA -> softmax -> BAR3 (lgkm: P,alpha visible) -> vmcnt(1) (V
// landed; K(kt+1) still flying) -> PV mfma -> issue V(kt+1) DMA (wave-private).
__global__ __launch_bounds__(512, 4) void k_flash(
    const unsigned short* __restrict__ qhg, const unsigned short* __restrict__ qlg,
    const unsigned short* __restrict__ khg, const unsigned short* __restrict__ klg,
    const unsigned short* __restrict__ vg,
    unsigned short* __restrict__ Opart, float* __restrict__ mlpart) {
  __shared__ __align__(16) char sm[65536];
  float* stf = (float*)sm;                             // [64][64] f32 S, swizzled
  char* stb = sm;                                      // P (bf16) aliases stf
  unsigned short* kh = (unsigned short*)(sm + 16384);  // [64][32] K hi
  unsigned short* kl = (unsigned short*)(sm + 20480);  // [64][32] K lo
  unsigned short* vt = (unsigned short*)(sm + 24576);  // [256][64] V
  float* alphaf = (float*)(sm + 57344);                // [64]
  float* otf = (float*)sm;                             // epilogue [256][64] f32

  // XCD-aware: blk%8 = XCD -> fixed (b,half) per XCD; per-XCD K/V ~1.3MB < L2.
  const int blk = blockIdx.x;
  const int b = (blk >> 1) & 3;
  const int half = blk & 1;
  const int qt_ = blk >> 3;
  const int q0 = qt_ * 64;
  const int jbase = half * 2048;
  const int t = threadIdx.x, lane = t & 63, w = t >> 6, h = lane >> 5;
  const int l31 = lane & 31;
  const int r_sm = t >> 3, p_sm = t & 7;
  const int mbs = (w >> 1) & 1, nbs = w & 1;

  // --- DMA source/dest addressing (pre-swizzled global -> linear LDS) ---
  // K: wave w<4 stages kh rows 16w..16w+15; w>=4 stages kl rows 16(w-4)..
  // lane l: row = 16*(w&3) + (l>>2), slot s = l&3 holds global granule s^(row&3)
  const int krow = 16 * (w & 3) + (lane >> 2);
  const int kg = (lane & 3) ^ (krow & 3);
  const unsigned short* kgsrc = ((w < 4) ? khg : klg) +
      (size_t)(b * N_ + jbase + krow) * CQK + kg * 8;
  unsigned short* kldst = ((w < 4) ? kh : kl) + (w & 3) * 512;  // 16 rows * 32
  // V: wave w stages its own rows [32w,32w+32) in 4 DMA ops (8 rows each).
  // lane l: row_local = l>>3, slot s = l&7 holds global granule s^(row&7)
  const int vc = 32 * w + (lane >> 3);
  const int vgg = (lane & 7) ^ ((lane >> 3) & 7);
  const unsigned short* vgsrc =
      vg + (size_t)(b * C_ + vc) * N_ + jbase + vgg * 8;
  unsigned short* vldst = vt + 32 * w * 64;

  // issue K(0), V(0)
  GL16(kgsrc, kldst);
#pragma unroll
  for (int q = 0; q < 4; ++q)
    GL16(vgsrc + q * 8 * N_, vldst + q * 8 * 64);

  // Q fragments straight from global (L2-resident), waves 0..3 only
  short8 qfh[2], qfl[2];
  {
    const unsigned short* qph =
        qhg + (size_t)(b * N_ + q0 + 32 * mbs + l31) * CQK + h * 8;
    const unsigned short* qpl =
        qlg + (size_t)(b * N_ + q0 + 32 * mbs + l31) * CQK + h * 8;
    if (w < 4) {
#pragma unroll
      for (int kk = 0; kk < 2; ++kk) {
        qfh[kk] = *(const short8*)(qph + kk * 16);
        qfl[kk] = *(const short8*)(qpl + kk * 16);
      }
    }
  }

  f32x16 acc0, acc1;
#pragma unroll
  for (int e = 0; e < 16; ++e) { acc0[e] = 0.f; acc1[e] = 0.f; }
  float m_run = -1e30f, l_run = 0.f;

  for (int kt = 0; kt < 32; ++kt) {
    // BAR1: K(kt) landed (4 newest = V in flight); prev P reads drained
    WAITCNT("vmcnt(4) lgkmcnt(0)");
    BARRIER();
    if (w < 4) {  // S = Q K^T, written swizzled to stf
      f32x16 sa;
#pragma unroll
      for (int e = 0; e < 16; ++e) sa[e] = 0.f;
      const int jn = 32 * nbs + l31;
      __builtin_amdgcn_s_setprio(1);
#pragma unroll
      for (int kk = 0; kk < 2; ++kk) {
        const short8 bh = *(const short8*)&kh[swz32(jn, kk * 16 + h * 8)];
        const short8 bl = *(const short8*)&kl[swz32(jn, kk * 16 + h * 8)];
        sa = mfma16(qfh[kk], bh, sa);
        sa = mfma16(qfh[kk], bl, sa);
        sa = mfma16(qfl[kk], bh, sa);
      }
      __builtin_amdgcn_s_setprio(0);
#pragma unroll
      for (int e = 0; e < 16; ++e) {
        const int ri = 32 * mbs + (e & 3) + 8 * (e >> 2) + 4 * h;
        stf[ri * 64 + ((((jn >> 2) ^ ri) & 15) << 2) + (jn & 3)] = sa[e];
      }
    }
    WAITCNT("lgkmcnt(0)");
    BARRIER();  // BAR2: S visible; K buffer free
    // issue K(kt+1) DMA (clamped re-stage at kt=31 keeps vmcnt counts uniform)
    {
      const int ktn = (kt + 1 < 32) ? kt + 1 : 31;
      GL16(kgsrc + ktn * 64 * CQK, kldst);
    }
    // online softmax: thread (r_sm,p_sm) owns cols [8p,8p+8) of row r_sm
    {
      float* p0 = stf + r_sm * 64 + ((((2 * p_sm) ^ r_sm) & 15) << 2);
      float* p1 = stf + r_sm * 64 + ((((2 * p_sm + 1) ^ r_sm) & 15) << 2);
      const f32x4 a0 = *(const f32x4*)p0;
      const f32x4 a1 = *(const f32x4*)p1;
      float s[8];
#pragma unroll
      for (int e = 0; e < 4; ++e) { s[e] = a0[e]; s[4 + e] = a1[e]; }
      float mx = s[0];
#pragma unroll
      for (int e = 1; e < 8; ++e) mx = fmaxf(mx, s[e]);
      mx = fmaxf(mx, __shfl_xor(mx, 1));
      mx = fmaxf(mx, __shfl_xor(mx, 2));
      mx = fmaxf(mx, __shfl_xor(mx, 4));
      const float mnew = fmaxf(m_run, mx);
      const float al = __expf(m_run - mnew);
      float ts = 0.f;
      short8 pv8;
#pragma unroll
      for (int e = 0; e < 8; ++e) {
        const float pe = __expf(s[e] - mnew);
        ts += pe;
        pv8[e] = (short)f2bf(pe);
      }
      ts += __shfl_xor(ts, 1);
      ts += __shfl_xor(ts, 2);
      ts += __shfl_xor(ts, 4);
      l_run = l_run * al + ts;
      m_run = mnew;
      *(short8*)p0 = pv8;  // P (bf16) overwrites the granule this thread read
      if (p_sm == 0) alphaf[r_sm] = al;
    }
    WAITCNT("lgkmcnt(0)");
    BARRIER();  // BAR3: P + alpha visible
    // rescale O by alpha[row]
#pragma unroll
    for (int eq = 0; eq < 4; ++eq) {
      const f32x4 av0 = *(const f32x4*)&alphaf[4 * h + 8 * eq];
      const f32x4 av1 = *(const f32x4*)&alphaf[32 + 4 * h + 8 * eq];
#pragma unroll
      for (int q = 0; q < 4; ++q) {
        acc0[4 * eq + q] *= av0[q];
        acc1[4 * eq + q] *= av1[q];
      }
    }
    // V(kt) landed (own-wave DMA; 1 newest = K(kt+1) still flying)
    WAITCNT("vmcnt(1)");
    // O += P * V^T (V from own wave-private LDS rows)
    {
      const int crow = 32 * w + l31;
      __builtin_amdgcn_s_setprio(1);
#pragma unroll
      for (int kk = 0; kk < 4; ++kk) {
        const int g0 = ((4 * kk + 2 * h) ^ l31) & 15;  // P col-granule swizzle
        const short8 pa0 = *(const short8*)(stb + l31 * 256 + (g0 << 4));
        const short8 pa1 = *(const short8*)(stb + (32 + l31) * 256 + (g0 << 4));
        const short8 vf = *(const short8*)&vt[swz64(crow, kk * 16 + h * 8)];
        acc0 = mfma16(pa0, vf, acc0);
        acc1 = mfma16(pa1, vf, acc1);
      }
      __builtin_amdgcn_s_setprio(0);
    }
    // own V reads drained, then issue V(kt+1) DMA into own rows (no barrier:
    // wave-private producer == consumer; visibility via vmcnt(1) next iter)
    WAITCNT("lgkmcnt(0)");
    {
      const int ktv = (kt + 1 < 32) ? kt + 1 : 31;
      const unsigned short* vs = vgsrc + ktv * 64;
#pragma unroll
      for (int q = 0; q < 4; ++q)
        GL16(vs + q * 8 * N_, vldst + q * 8 * 64);
    }
  }

  // write per-row stats (m,l); O stays unnormalized (combine divides)
  if (p_sm == 0) {
    mlpart[blk * 128 + r_sm] = m_run;
    mlpart[blk * 128 + 64 + r_sm] = l_run;
  }
  // drain ALL in-flight DMA (clamped re-stages target vt/kh which otf reuses)
  WAITCNT("vmcnt(0) lgkmcnt(0)");
  BARRIER();
  // transpose O through LDS, store f16 partials [c][i]
  {
    const int cc = 32 * w + l31;
#pragma unroll
    for (int e = 0; e < 16; ++e) {
      const int r0 = (e & 3) + 8 * (e >> 2) + 4 * h;
      otf[cc * 64 + ((((r0 >> 2) ^ cc) & 15) << 2) + (r0 & 3)] = acc0[e];
      const int r1 = 32 + r0;
      otf[cc * 64 + ((((r1 >> 2) ^ cc) & 15) << 2) + (r1 & 3)] = acc1[e];
    }
  }
  WAITCNT("lgkmcnt(0)");
  BARRIER();  // otf visible cross-wave
#pragma unroll
  for (int pass = 0; pass < 8; ++pass) {
    const int idx = pass * 512 + t;
    const int c = idx >> 4, gi = idx & 15;
    const f32x4 ov = *(const f32x4*)(otf + c * 64 + (((gi ^ c) & 15) << 2));
    short4v hv;
#pragma unroll
    for (int q = 0; q < 4; ++q) {
      const _Float16 hf = (_Float16)ov[q];
      hv[q] = __builtin_bit_cast(short, hf);
    }
    *(short4v*)(Opart + blk * 16384 + c * 64 + gi * 4) = hv;
  }
}

// ---------------- kernel 4: combine halves + residual ----------------
__global__ __launch_bounds__(256) void k_combine(
    const unsigned short* __restrict__ Opart, const float* __restrict__ mlpart,
    const float* __restrict__ x, const float* __restrict__ gamma,
    float* __restrict__ out) {
  const int cb = blockIdx.x;
  const int b = cb & 3, qt_ = cb >> 2;
  const int q0 = qt_ * 64;
  const int blk1 = (qt_ << 3) | (b << 1);
  const int blk2 = blk1 | 1;
  const int t = threadIdx.x;
  const int i = t & 63, cg = t >> 6;

  const float m1 = mlpart[blk1 * 128 + i], l1 = mlpart[blk1 * 128 + 64 + i];
  const float m2 = mlpart[blk2 * 128 + i], l2 = mlpart[blk2 * 128 + 64 + i];
  const float M = fmaxf(m1, m2);
  const float w1 = __expf(m1 - M), w2 = __expf(m2 - M);
  const float inv = 1.f / (w1 * l1 + w2 * l2);
  const float gm = gamma[0];
  const float s1 = gm * w1 * inv, s2 = gm * w2 * inv;

  const unsigned short* p1 = Opart + blk1 * 16384 + i;
  const unsigned short* p2 = Opart + blk2 * 16384 + i;
#pragma unroll 4
  for (int c = cg; c < C_; c += 4) {
    const float o1 = (float)__builtin_bit_cast(_Float16, p1[c * 64]);
    const float o2 = (float)__builtin_bit_cast(_Float16, p2[c * 64]);
    const int g = (b * C_ + c) * N_ + q0 + i;
    out[g] = s1 * o1 + s2 * o2 + x[g];
  }
}

// ---------------- launch ----------------
extern "C" void kernel_launch(void* const* d_in, const int* in_sizes, int n_in,
                              void* d_out, int out_size, void* d_ws, size_t ws_size,
                              hipStream_t stream) {
  const float* x     = (const float*)d_in[0];
  const float* Wq    = (const float*)d_in[1];
  const float* bq    = (const float*)d_in[2];
  const float* Wk    = (const float*)d_in[3];
  const float* bk    = (const float*)d_in[4];
  const float* Wv    = (const float*)d_in[5];
  const float* bv    = (const float*)d_in[6];
  const float* gamma = (const float*)d_in[7];
  float* out = (float*)d_out;
  (void)in_sizes; (void)n_in; (void)out_size; (void)ws_size;

  char* ws = (char*)d_ws;
  size_t off = 0;
  auto carve = [&](size_t bytes) -> char* {
    char* p = ws + off;
    off += (bytes + 255) & ~(size_t)255;
    return p;
  };
  unsigned short* xthi = (unsigned short*)carve((size_t)B_ * N_ * C_ * 2);
  unsigned short* xtlo = (unsigned short*)carve((size_t)B_ * N_ * C_ * 2);
  unsigned short* wqh  = (unsigned short*)carve(32 * 256 * 2);
  unsigned short* wql  = (unsigned short*)carve(32 * 256 * 2);
  unsigned short* wkh  = (unsigned short*)carve(32 * 256 * 2);
  unsigned short* wkl  = (unsigned short*)carve(32 * 256 * 2);
  unsigned short* wvh  = (unsigned short*)carve(256 * 256 * 2);
  unsigned short* wvl  = (unsigned short*)carve(256 * 256 * 2);
  unsigned short* qhg  = (unsigned short*)carve((size_t)B_ * N_ * CQK * 2);
  unsigned short* qlg  = (unsigned short*)carve((size_t)B_ * N_ * CQK * 2);
  unsigned short* khg  = (unsigned short*)carve((size_t)B_ * N_ * CQK * 2);
  unsigned short* klg  = (unsigned short*)carve((size_t)B_ * N_ * CQK * 2);
  unsigned short* vg   = (unsigned short*)carve((size_t)B_ * C_ * N_ * 2);
  unsigned short* Opart = (unsigned short*)carve((size_t)512 * 16384 * 2);  // f16
  float* mlpart = (float*)carve((size_t)512 * 128 * 4);

  k_prep<<<1344, 256, 0, stream>>>(x, xthi, xtlo, Wq, Wk, Wv,
                                   wqh, wql, wkh, wkl, wvh, wvl);
  k_proj<<<dim3(64, 5, B_), 256, 0, stream>>>(wqh, wql, wkh, wkl, wvh, wvl,
                                              xthi, xtlo, bq, bk, bv,
                                              qhg, qlg, khg, klg, vg);
  k_flash<<<512, 512, 0, stream>>>(qhg, qlg, khg, klg, vg, Opart, mlpart);
  k_combine<<<256, 256, 0, stream>>>(Opart, mlpart, x, gamma, out);
}

// Round 3
// 188.470 us; speedup vs baseline: 1.2925x; 1.0622x over previous
//
#include <hip/hip_runtime.h>

// SelfAttention (B=4, C=256, H=W=64): fused projections + split-K flash attention.
// Round 6: r5 (110us) was still 3-barrier phase-serialized with a full f32 S
// round-trip through LDS. This round restructures k_flash:
//  - swapped QK^T (mfma(K,Q)): each lane owns a full P row-half in registers ->
//    softmax is lane-local (31 fmax + shfl_xor(32) + 32 exp), no S LDS round trip.
//  - producer/consumer waves: 12-wave blocks = 8 PV waves (c-split) + 2
//    alternating S-pairs; S(kt+1) runs concurrently with PV(kt); P double-
//    buffered (2x8KB bf16); (m,l) handed between pairs via LDS; ONE barrier/iter.
//  - V and K load global->VGPR as contiguous 16B fragments (no reuse -> no LDS,
//    no DMA, no vmcnt coupling). LDS 64KB -> 17.9KB.
//  - epilogue: acc stored lane-major (coalesced); k_combine index-adapted.

#define B_ 4
#define C_ 256
#define N_ 4096
#define CQK 32

typedef __attribute__((ext_vector_type(8))) short short8;
typedef __attribute__((ext_vector_type(4))) short short4v;
typedef __attribute__((ext_vector_type(16))) float f32x16;
typedef __attribute__((ext_vector_type(4))) float f32x4;

__device__ __forceinline__ unsigned short f2bf(float f) {
  unsigned int u = __builtin_bit_cast(unsigned int, f);
  u = (u + 0x7fffu + ((u >> 16) & 1u)) >> 16;  // RNE
  return (unsigned short)u;
}
__device__ __forceinline__ float bf2f(unsigned short s) {
  unsigned int u = ((unsigned int)s) << 16;
  return __builtin_bit_cast(float, u);
}
__device__ __forceinline__ short f32tof16(float f) {
  const _Float16 hf = (_Float16)f;
  return __builtin_bit_cast(short, hf);
}
__device__ __forceinline__ f32x16 mfma16(short8 a, short8 b, f32x16 c) {
  return __builtin_amdgcn_mfma_f32_32x32x16_bf16(a, b, c, 0, 0, 0);
}
// swizzled element index into bf16 LDS tiles (16B granules XORed by row)
__device__ __forceinline__ int swz64(int row, int col) {  // rows of 64 bf16
  return row * 64 + ((((col >> 3) ^ row) & 7) << 3) + (col & 7);
}

#define WAITCNT(s) asm volatile("s_waitcnt " s ::: "memory")
#define BARRIER()                         \
  do {                                    \
    __builtin_amdgcn_s_barrier();         \
    asm volatile("" ::: "memory");        \
  } while (0)

// ---------------- kernel 1: prep (x transpose+split, weight splits) ----------
__global__ __launch_bounds__(256) void k_prep(
    const float* __restrict__ x, unsigned short* __restrict__ xthi,
    unsigned short* __restrict__ xtlo,
    const float* __restrict__ Wq, const float* __restrict__ Wk,
    const float* __restrict__ Wv,
    unsigned short* __restrict__ wqh, unsigned short* __restrict__ wql,
    unsigned short* __restrict__ wkh, unsigned short* __restrict__ wkl,
    unsigned short* __restrict__ wvh, unsigned short* __restrict__ wvl) {
  __shared__ __align__(16) float tile[64 * 65];
  const int bi = blockIdx.x;
  const int t = threadIdx.x;
  if (bi < 1024) {
    const int it = bi & 63, ct = (bi >> 6) & 3, b = bi >> 8;
    const int i0 = it * 64, c0 = ct * 64;
    {
      const int i = t & 63, cb = t >> 6;
#pragma unroll
      for (int z = 0; z < 16; ++z) {
        const int c = z * 4 + cb;
        tile[i * 65 + c] = x[(b * C_ + c0 + c) * N_ + i0 + i];
      }
    }
    __syncthreads();
    {
      const int ii = t >> 2, p = t & 3;
      short8 h0, h1, l0, l1;
#pragma unroll
      for (int e = 0; e < 16; ++e) {
        const float f = tile[ii * 65 + p * 16 + e];
        const unsigned short hb = f2bf(f);
        const unsigned short lb = f2bf(f - bf2f(hb));
        if (e < 8) { h0[e] = (short)hb; l0[e] = (short)lb; }
        else       { h1[e - 8] = (short)hb; l1[e - 8] = (short)lb; }
      }
      const int base = (b * N_ + i0 + ii) * C_ + c0 + p * 16;
      *(short8*)(xthi + base) = h0;
      *(short8*)(xthi + base + 8) = h1;
      *(short8*)(xtlo + base) = l0;
      *(short8*)(xtlo + base + 8) = l1;
    }
  } else {
    const int e = (bi - 1024) * 256 + t;  // < 81920
    const float* src; unsigned short *hi, *lo; int idx;
    if (e < 8192)        { src = Wq; hi = wqh; lo = wql; idx = e; }
    else if (e < 16384)  { src = Wk; hi = wkh; lo = wkl; idx = e - 8192; }
    else                 { src = Wv; hi = wvh; lo = wvl; idx = e - 16384; }
    const float f = src[idx];
    const unsigned short h = f2bf(f);
    hi[idx] = h;
    lo[idx] = f2bf(f - bf2f(h));
  }
}

// ---------------- kernel 2: fused q/k/v projection GEMM ----------------
__global__ __launch_bounds__(256) void k_proj(
    const unsigned short* __restrict__ wqh, const unsigned short* __restrict__ wql,
    const unsigned short* __restrict__ wkh, const unsigned short* __restrict__ wkl,
    const unsigned short* __restrict__ wvh, const unsigned short* __restrict__ wvl,
    const unsigned short* __restrict__ xthi, const unsigned short* __restrict__ xtlo,
    const float* __restrict__ bq, const float* __restrict__ bk,
    const float* __restrict__ bv,
    unsigned short* __restrict__ qhg, unsigned short* __restrict__ qlg,
    unsigned short* __restrict__ khg, unsigned short* __restrict__ klg,
    unsigned short* __restrict__ vg) {
  __shared__ __align__(16) char sm[33792];
  unsigned short* awh = (unsigned short*)sm;       // [64][64] W hi (swizzled)
  unsigned short* awl = awh + 4096;
  unsigned short* bxh = awl + 4096;                // [64][64] x^T hi
  unsigned short* bxl = bxh + 4096;
  float* qt = (float*)sm;                          // epilogue reuse: [64][65] f32

  const int it = blockIdx.x, ot = blockIdx.y, b = blockIdx.z;
  const int i0 = it * 64, o0 = ot * 64;
  const int t = threadIdx.x, lane = t & 63, w = t >> 6, h = lane >> 5;
  const int mb = w >> 1, nb = w & 1;
  const int srow = t >> 2, sp = t & 3;

  const int og = o0 + srow;
  const unsigned short *wh, *wl;
  if (og < 32)      { wh = wqh + og * C_;        wl = wql + og * C_; }
  else if (og < 64) { wh = wkh + (og - 32) * C_; wl = wkl + (og - 32) * C_; }
  else              { wh = wvh + (og - 64) * C_; wl = wvl + (og - 64) * C_; }
  const unsigned short* xh = xthi + (b * N_ + i0 + srow) * C_;
  const unsigned short* xl = xtlo + (b * N_ + i0 + srow) * C_;

  f32x16 acc;
#pragma unroll
  for (int e = 0; e < 16; ++e) acc[e] = 0.f;
  const int m = 32 * mb + (lane & 31);
  const int n = 32 * nb + (lane & 31);

  for (int kt = 0; kt < 4; ++kt) {
    const int cb = kt * 64 + sp * 16;
    *(short8*)&awh[swz64(srow, sp * 16)]     = *(const short8*)(wh + cb);
    *(short8*)&awh[swz64(srow, sp * 16 + 8)] = *(const short8*)(wh + cb + 8);
    *(short8*)&awl[swz64(srow, sp * 16)]     = *(const short8*)(wl + cb);
    *(short8*)&awl[swz64(srow, sp * 16 + 8)] = *(const short8*)(wl + cb + 8);
    *(short8*)&bxh[swz64(srow, sp * 16)]     = *(const short8*)(xh + cb);
    *(short8*)&bxh[swz64(srow, sp * 16 + 8)] = *(const short8*)(xh + cb + 8);
    *(short8*)&bxl[swz64(srow, sp * 16)]     = *(const short8*)(xl + cb);
    *(short8*)&bxl[swz64(srow, sp * 16 + 8)] = *(const short8*)(xl + cb + 8);
    __syncthreads();
#pragma unroll
    for (int kk = 0; kk < 4; ++kk) {
      const int kb = kk * 16 + h * 8;
      const short8 ah  = *(const short8*)&awh[swz64(m, kb)];
      const short8 al2 = *(const short8*)&awl[swz64(m, kb)];
      const short8 bh  = *(const short8*)&bxh[swz64(n, kb)];
      const short8 bl2 = *(const short8*)&bxl[swz64(n, kb)];
      acc = mfma16(ah, bh, acc);   // hi*hi
      acc = mfma16(ah, bl2, acc);  // hi*lo
      acc = mfma16(al2, bh, acc);  // lo*hi
    }
    __syncthreads();
  }

  if (ot > 0) {  // v epilogue: direct [B][C][N] bf16 store
#pragma unroll
    for (int e = 0; e < 16; ++e) {
      const int r = 32 * mb + (e & 3) + 8 * (e >> 2) + 4 * h;
      const int oc = o0 - 64 + r;
      vg[(b * C_ + oc) * N_ + i0 + n] = f2bf(acc[e] + bv[oc]);
    }
  } else {  // q/k epilogue: LDS transpose -> [B][N][32] hi/lo
#pragma unroll
    for (int e = 0; e < 16; ++e) {
      const int r = 32 * mb + (e & 3) + 8 * (e >> 2) + 4 * h;
      const float bias = (r < 32) ? bq[r] : bk[r - 32];
      qt[r * 65 + n] = acc[e] + bias;
    }
    __syncthreads();
    const int ii = t >> 2;
    short8 hv0, hv1, lv0, lv1;
#pragma unroll
    for (int e = 0; e < 16; ++e) {
      const float f = qt[(sp * 16 + e) * 65 + ii];
      const unsigned short hb = f2bf(f);
      const unsigned short lb = f2bf(f - bf2f(hb));
      if (e < 8) { hv0[e] = (short)hb; lv0[e] = (short)lb; }
      else       { hv1[e - 8] = (short)hb; lv1[e - 8] = (short)lb; }
    }
    if (sp < 2) {
      const int base = (b * N_ + i0 + ii) * CQK + sp * 16;
      *(short8*)(qhg + base) = hv0; *(short8*)(qhg + base + 8) = hv1;
      *(short8*)(qlg + base) = lv0; *(short8*)(qlg + base + 8) = lv1;
    } else {
      const int base = (b * N_ + i0 + ii) * CQK + sp * 16 - 32;
      *(short8*)(khg + base) = hv0; *(short8*)(khg + base + 8) = hv1;
      *(short8*)(klg + base) = lv0; *(short8*)(klg + base + 8) = lv1;
    }
  }
}

// ---------------- kernel 3: producer/consumer flash attention ----------------
// 512 blocks x 768 threads. blk = (qt<<3)|(b<<1)|half (XCD-aware).
// Waves 0-7: PV consumers, c-block = 32w. Waves 8-11: S producers, two
// alternating pairs (waves 8,9 = pair0: even target tiles; 10,11 = pair1: odd).
// Iter kt: PV(kt) reads Pbuf[kt&1]/alpha[kt&1]; active S pair computes
// S(kt+1) swapped (mfma(K,Q)), in-register softmax, writes Pbuf[(kt+1)&1],
// alpha, and hands (m,l) to the other pair via mlm LDS. One barrier per iter.
// P LDS layout: [64 rows][8 granules of 16B], granule phys = (j>>3) ^ (row&7).
// Opart layout: [blk][wave 8][lane 64][32 f16] = acc0[e0..15],acc1[e0..15].
__global__ __launch_bounds__(768, 3) void k_flash(
    const unsigned short* __restrict__ qhg, const unsigned short* __restrict__ qlg,
    const unsigned short* __restrict__ khg, const unsigned short* __restrict__ klg,
    const unsigned short* __restrict__ vg,
    unsigned short* __restrict__ Opart, float* __restrict__ mlpart) {
  __shared__ __align__(16) char sm[17920];
  char* Pb0 = sm;                          // [64][128B] bf16 P, swizzled
  char* Pb1 = sm + 8192;
  float* alphaA = (float*)(sm + 16384);    // [2][64]
  float* mlm = (float*)(sm + 16896);       // [2][m:64 | l:64]

  const int blk = blockIdx.x;
  const int b = (blk >> 1) & 3;
  const int half = blk & 1;
  const int qt_ = blk >> 3;
  const int q0 = qt_ * 64;
  const int jbase = half * 2048;
  const int t = threadIdx.x, lane = t & 63, w = t >> 6, h = lane >> 5;
  const int l31 = lane & 31;

  if (w < 8) {
    // ================= PV consumer =================
    const int c = 32 * w + l31;
    const unsigned short* vsrc = vg + (size_t)(b * C_ + c) * N_ + jbase + h * 8;
    f32x16 acc0, acc1;
#pragma unroll
    for (int e = 0; e < 16; ++e) { acc0[e] = 0.f; acc1[e] = 0.f; }
    short8 vf[4];
#pragma unroll
    for (int kk = 0; kk < 4; ++kk)
      vf[kk] = *(const short8*)(vsrc + kk * 16);  // V(0)
    WAITCNT("lgkmcnt(0)");
    BARRIER();  // prologue: P(0)/alpha(0) ready

#pragma unroll 2
    for (int kt = 0; kt < 32; ++kt) {
      const char* pb = (kt & 1) ? Pb1 : Pb0;
      const float* alp = alphaA + (kt & 1) * 64;
      // rescale O by alpha[row]
#pragma unroll
      for (int eq = 0; eq < 4; ++eq) {
        const f32x4 av0 = *(const f32x4*)(alp + 8 * eq + 4 * h);
        const f32x4 av1 = *(const f32x4*)(alp + 32 + 8 * eq + 4 * h);
#pragma unroll
        for (int q = 0; q < 4; ++q) {
          acc0[4 * eq + q] *= av0[q];
          acc1[4 * eq + q] *= av1[q];
        }
      }
      // O += P * V
      __builtin_amdgcn_s_setprio(1);
#pragma unroll
      for (int kk = 0; kk < 4; ++kk) {
        const int phys = (2 * kk + h) ^ (l31 & 7);
        const short8 pa0 = *(const short8*)(pb + l31 * 128 + phys * 16);
        const short8 pa1 = *(const short8*)(pb + (32 + l31) * 128 + phys * 16);
        acc0 = mfma16(pa0, vf[kk], acc0);
        acc1 = mfma16(pa1, vf[kk], acc1);
      }
      __builtin_amdgcn_s_setprio(0);
      // load V(kt+1) straight to regs (contiguous 16B frags; L2-resident)
      if (kt + 1 < 32) {
#pragma unroll
        for (int kk = 0; kk < 4; ++kk)
          vf[kk] = *(const short8*)(vsrc + (kt + 1) * 64 + kk * 16);
      }
      WAITCNT("lgkmcnt(0)");
      BARRIER();
    }
    // epilogue: lane-major coalesced store (32 f16 per lane, contiguous)
    {
      unsigned short* dst = Opart + (size_t)blk * 16384 + (w * 64 + lane) * 32;
      short8 o0, o1, o2, o3;
#pragma unroll
      for (int e = 0; e < 8; ++e) {
        o0[e] = f32tof16(acc0[e]);
        o1[e] = f32tof16(acc0[8 + e]);
        o2[e] = f32tof16(acc1[e]);
        o3[e] = f32tof16(acc1[8 + e]);
      }
      *(short8*)(dst) = o0;
      *(short8*)(dst + 8) = o1;
      *(short8*)(dst + 16) = o2;
      *(short8*)(dst + 24) = o3;
    }
  } else {
    // ================= S producer =================
    const int sw = w - 8;
    const int pair = sw >> 1;   // 0: even tiles, 1: odd tiles
    const int rb = sw & 1;      // row block (32 rows)
    const int srow = rb * 32 + l31;
    // Q fragments (persistent): B-operand, lane = q-row
    short8 qfh[2], qfl[2];
    {
      const unsigned short* qph = qhg + (size_t)(b * N_ + q0 + srow) * CQK + h * 8;
      const unsigned short* qpl = qlg + (size_t)(b * N_ + q0 + srow) * CQK + h * 8;
#pragma unroll
      for (int kk = 0; kk < 2; ++kk) {
        qfh[kk] = *(const short8*)(qph + kk * 16);
        qfl[kk] = *(const short8*)(qpl + kk * 16);
      }
    }
    // K fragment base: A-operand, lane = key-row (within 32-tile)
    const unsigned short* kph = khg + (size_t)(b * N_ + jbase + l31) * CQK + h * 8;
    const unsigned short* kpl = klg + (size_t)(b * N_ + jbase + l31) * CQK + h * 8;
    short8 kfh[2][2], kfl[2][2];  // [jt][kk]
    float m_run = -1e30f, l_run = 0.f;

    auto loadK = [&](int tau) {
#pragma unroll
      for (int jt = 0; jt < 2; ++jt)
#pragma unroll
        for (int kk = 0; kk < 2; ++kk) {
          kfh[jt][kk] = *(const short8*)(kph + tau * 2048 + jt * 1024 + kk * 16);
          kfl[jt][kk] = *(const short8*)(kpl + tau * 2048 + jt * 1024 + kk * 16);
        }
    };
    auto s_step = [&](int tau) {
      f32x16 s0, s1;  // S^T tiles: rows=j', cols=q-row (lane)
#pragma unroll
      for (int e = 0; e < 16; ++e) { s0[e] = 0.f; s1[e] = 0.f; }
      __builtin_amdgcn_s_setprio(1);
#pragma unroll
      for (int kk = 0; kk < 2; ++kk) {
        s0 = mfma16(kfh[0][kk], qfh[kk], s0);
        s0 = mfma16(kfh[0][kk], qfl[kk], s0);
        s0 = mfma16(kfl[0][kk], qfh[kk], s0);
        s1 = mfma16(kfh[1][kk], qfh[kk], s1);
        s1 = mfma16(kfh[1][kk], qfl[kk], s1);
        s1 = mfma16(kfl[1][kk], qfh[kk], s1);
      }
      __builtin_amdgcn_s_setprio(0);
      if (tau + 2 < 32) loadK(tau + 2);  // this pair's next target
      // online softmax, lane-local (lane holds 32 of 64 j; partner = lane^32)
      float mprev, lprev;
      if (tau == 0) { mprev = -1e30f; lprev = 0.f; }
      else {
        mprev = mlm[((tau + 1) & 1) * 128 + srow];
        lprev = mlm[((tau + 1) & 1) * 128 + 64 + srow];
      }
      float mx = s0[0];
#pragma unroll
      for (int e = 1; e < 16; ++e) mx = fmaxf(mx, s0[e]);
#pragma unroll
      for (int e = 0; e < 16; ++e) mx = fmaxf(mx, s1[e]);
      mx = fmaxf(mx, __shfl_xor(mx, 32));
      const float mnew = fmaxf(mprev, mx);
      const float al = __expf(mprev - mnew);
      float ts = 0.f;
#pragma unroll
      for (int e = 0; e < 16; ++e) { s0[e] = __expf(s0[e] - mnew); ts += s0[e]; }
#pragma unroll
      for (int e = 0; e < 16; ++e) { s1[e] = __expf(s1[e] - mnew); ts += s1[e]; }
      ts += __shfl_xor(ts, 32);
      const float lnew = lprev * al + ts;
      m_run = mnew;
      l_run = lnew;
      // write P (bf16) to buf[tau&1]: quad (jt,q) -> j = jt*32+8q+4h+(0..3)
      char* Pw = (tau & 1) ? Pb1 : Pb0;
#pragma unroll
      for (int q = 0; q < 4; ++q) {
        short4v p0, p1;
        p0[0] = (short)f2bf(s0[4 * q]);     p0[1] = (short)f2bf(s0[4 * q + 1]);
        p0[2] = (short)f2bf(s0[4 * q + 2]); p0[3] = (short)f2bf(s0[4 * q + 3]);
        p1[0] = (short)f2bf(s1[4 * q]);     p1[1] = (short)f2bf(s1[4 * q + 1]);
        p1[2] = (short)f2bf(s1[4 * q + 2]); p1[3] = (short)f2bf(s1[4 * q + 3]);
        const int ph0 = q ^ (srow & 7);        // jt=0: granule q
        const int ph1 = (4 + q) ^ (srow & 7);  // jt=1: granule 4+q
        *(short4v*)(Pw + srow * 128 + ph0 * 16 + 8 * h) = p0;
        *(short4v*)(Pw + srow * 128 + ph1 * 16 + 8 * h) = p1;
      }
      if (h == 0) {
        alphaA[(tau & 1) * 64 + srow] = al;
        mlm[(tau & 1) * 128 + srow] = mnew;
        mlm[(tau & 1) * 128 + 64 + srow] = lnew;
      }
    };

    // prologue: pair0 produces tile 0; pair1 preloads K(1)
    loadK(pair);
    if (pair == 0) s_step(0);  // also issues loadK(2)
    WAITCNT("lgkmcnt(0)");
    BARRIER();

#pragma unroll 2
    for (int kt = 0; kt < 32; ++kt) {
      const int tau = kt + 1;
      if (tau < 32 && (tau & 1) == pair) s_step(tau);
      WAITCNT("lgkmcnt(0)");
      BARRIER();
    }
    // pair1 holds the final (m,l) after tau=31
    if (pair == 1 && h == 0) {
      mlpart[blk * 128 + srow] = m_run;
      mlpart[blk * 128 + 64 + srow] = l_run;
    }
  }
}

// ---------------- kernel 4: combine halves + residual ----------------
// Opart layout: [blk][w 8][lane 64][32 f16]; for output row i (0..63):
// lane = (c&31) + 32*((i>>2)&1), slot = 16*(i>>5) + 4*((i&31)>>3) + (i&3).
__global__ __launch_bounds__(256) void k_combine(
    const unsigned short* __restrict__ Opart, const float* __restrict__ mlpart,
    const float* __restrict__ x, const float* __restrict__ gamma,
    float* __restrict__ out) {
  const int cb = blockIdx.x;
  const int b = cb & 3, qt_ = cb >> 2;
  const int q0 = qt_ * 64;
  const int blk1 = (qt_ << 3) | (b << 1);
  const int blk2 = blk1 | 1;
  const int t = threadIdx.x;
  const int i = t & 63, cg = t >> 6;

  const float m1 = mlpart[blk1 * 128 + i], l1 = mlpart[blk1 * 128 + 64 + i];
  const float m2 = mlpart[blk2 * 128 + i], l2 = mlpart[blk2 * 128 + 64 + i];
  const float M = fmaxf(m1, m2);
  const float w1 = __expf(m1 - M), w2 = __expf(m2 - M);
  const float inv = 1.f / (w1 * l1 + w2 * l2);
  const float gm = gamma[0];
  const float s1 = gm * w1 * inv, s2 = gm * w2 * inv;

  const int hh = (i >> 2) & 1;
  const int s = ((i >> 5) << 4) + (((i & 31) >> 3) << 2) + (i & 3);
  const unsigned short* p1 = Opart + (size_t)blk1 * 16384 + hh * 1024 + s;
  const unsigned short* p2 = Opart + (size_t)blk2 * 16384 + hh * 1024 + s;
#pragma unroll 4
  for (int c = cg; c < C_; c += 4) {
    const int lb = (c >> 5) * 2048 + (c & 31) * 32;
    const float o1 = (float)__builtin_bit_cast(_Float16, p1[lb]);
    const float o2 = (float)__builtin_bit_cast(_Float16, p2[lb]);
    const int g = (b * C_ + c) * N_ + q0 + i;
    out[g] = s1 * o1 + s2 * o2 + x[g];
  }
}

// ---------------- launch ----------------
extern "C" void kernel_launch(void* const* d_in, const int* in_sizes, int n_in,
                              void* d_out, int out_size, void* d_ws, size_t ws_size,
                              hipStream_t stream) {
  const float* x     = (const float*)d_in[0];
  const float* Wq    = (const float*)d_in[1];
  const float* bq    = (const float*)d_in[2];
  const float* Wk    = (const float*)d_in[3];
  const float* bk    = (const float*)d_in[4];
  const float* Wv    = (const float*)d_in[5];
  const float* bv    = (const float*)d_in[6];
  const float* gamma = (const float*)d_in[7];
  float* out = (float*)d_out;
  (void)in_sizes; (void)n_in; (void)out_size; (void)ws_size;

  char* ws = (char*)d_ws;
  size_t off = 0;
  auto carve = [&](size_t bytes) -> char* {
    char* p = ws + off;
    off += (bytes + 255) & ~(size_t)255;
    return p;
  };
  unsigned short* xthi = (unsigned short*)carve((size_t)B_ * N_ * C_ * 2);
  unsigned short* xtlo = (unsigned short*)carve((size_t)B_ * N_ * C_ * 2);
  unsigned short* wqh  = (unsigned short*)carve(32 * 256 * 2);
  unsigned short* wql  = (unsigned short*)carve(32 * 256 * 2);
  unsigned short* wkh  = (unsigned short*)carve(32 * 256 * 2);
  unsigned short* wkl  = (unsigned short*)carve(32 * 256 * 2);
  unsigned short* wvh  = (unsigned short*)carve(256 * 256 * 2);
  unsigned short* wvl  = (unsigned short*)carve(256 * 256 * 2);
  unsigned short* qhg  = (unsigned short*)carve((size_t)B_ * N_ * CQK * 2);
  unsigned short* qlg  = (unsigned short*)carve((size_t)B_ * N_ * CQK * 2);
  unsigned short* khg  = (unsigned short*)carve((size_t)B_ * N_ * CQK * 2);
  unsigned short* klg  = (unsigned short*)carve((size_t)B_ * N_ * CQK * 2);
  unsigned short* vg   = (unsigned short*)carve((size_t)B_ * C_ * N_ * 2);
  unsigned short* Opart = (unsigned short*)carve((size_t)512 * 16384 * 2);  // f16
  float* mlpart = (float*)carve((size_t)512 * 128 * 4);

  k_prep<<<1344, 256, 0, stream>>>(x, xthi, xtlo, Wq, Wk, Wv,
                                   wqh, wql, wkh, wkl, wvh, wvl);
  k_proj<<<dim3(64, 5, B_), 256, 0, stream>>>(wqh, wql, wkh, wkl, wvh, wvl,
                                              xthi, xtlo, bq, bk, bv,
                                              qhg, qlg, khg, klg, vg);
  k_flash<<<512, 768, 0, stream>>>(qhg, qlg, khg, klg, vg, Opart, mlpart);
  k_combine<<<256, 256, 0, stream>>>(Opart, mlpart, x, gamma, out);
}

// Round 4
// 187.913 us; speedup vs baseline: 1.2964x; 1.0030x over previous
//
#include <hip/hip_runtime.h>

// SelfAttention (B=4, C=256, H=W=64): fused projections + split-K flash attention.
// Round 7: r6 (94us) was LDS-pipe + convoy bound: 8 PV waves each re-read the
// full 8KB P tile + 8 alpha vectors per iter; S pairs handed (m,l) through LDS
// every tile; __expf + manual RNE pack ~450 VALU/step. This round:
//  - 4 FAT PV waves (64 channels each): P fragments reused across 2 c-blocks ->
//    P/alpha LDS traffic halved, 16 MFMA per wave per tile.
//  - 2 row-split S producers (rows 0-31 / 32-63), each does EVERY tile ->
//    (m,l) chain lives in registers of one wave, no LDS stats handoff.
//  - log2-domain softmax (Wq,bq pre-scaled by log2e) -> exp2 only.
//  - v_cvt_pk_bf16_f32 for P pack; tree max/sum (depth 5 vs 31-chain).
//  - defer-rescale: per-half "max changed" flag; PV skips rescale when unset
//    (exact: unset <=> all alphas == 1.0).
// Block = 384 thr (6 waves), 1 barrier/tile, P double-buffered.

#define B_ 4
#define C_ 256
#define N_ 4096
#define CQK 32
#define LOG2E 1.44269504088896340736f

typedef __attribute__((ext_vector_type(8))) short short8;
typedef __attribute__((ext_vector_type(4))) short short4v;
typedef __attribute__((ext_vector_type(2))) unsigned int uint2v;
typedef __attribute__((ext_vector_type(16))) float f32x16;
typedef __attribute__((ext_vector_type(4))) float f32x4;

__device__ __forceinline__ unsigned short f2bf(float f) {
  unsigned int u = __builtin_bit_cast(unsigned int, f);
  u = (u + 0x7fffu + ((u >> 16) & 1u)) >> 16;  // RNE
  return (unsigned short)u;
}
__device__ __forceinline__ float bf2f(unsigned short s) {
  unsigned int u = ((unsigned int)s) << 16;
  return __builtin_bit_cast(float, u);
}
__device__ __forceinline__ short f32tof16(float f) {
  const _Float16 hf = (_Float16)f;
  return __builtin_bit_cast(short, hf);
}
// pack two f32 -> two bf16 (RNE), one instruction
__device__ __forceinline__ unsigned int cvtpk(float lo, float hi) {
  unsigned int r;
  asm("v_cvt_pk_bf16_f32 %0, %1, %2" : "=v"(r) : "v"(lo), "v"(hi));
  return r;
}
__device__ __forceinline__ f32x16 mfma16(short8 a, short8 b, f32x16 c) {
  return __builtin_amdgcn_mfma_f32_32x32x16_bf16(a, b, c, 0, 0, 0);
}
// swizzled element index into bf16 LDS tiles (16B granules XORed by row)
__device__ __forceinline__ int swz64(int row, int col) {  // rows of 64 bf16
  return row * 64 + ((((col >> 3) ^ row) & 7) << 3) + (col & 7);
}

#define WAITCNT(s) asm volatile("s_waitcnt " s ::: "memory")
#define BARRIER()                         \
  do {                                    \
    __builtin_amdgcn_s_barrier();         \
    asm volatile("" ::: "memory");        \
  } while (0)

// ---------------- kernel 1: prep (x transpose+split, weight splits) ----------
__global__ __launch_bounds__(256) void k_prep(
    const float* __restrict__ x, unsigned short* __restrict__ xthi,
    unsigned short* __restrict__ xtlo,
    const float* __restrict__ Wq, const float* __restrict__ Wk,
    const float* __restrict__ Wv,
    unsigned short* __restrict__ wqh, unsigned short* __restrict__ wql,
    unsigned short* __restrict__ wkh, unsigned short* __restrict__ wkl,
    unsigned short* __restrict__ wvh, unsigned short* __restrict__ wvl) {
  __shared__ __align__(16) float tile[64 * 65];
  const int bi = blockIdx.x;
  const int t = threadIdx.x;
  if (bi < 1024) {
    const int it = bi & 63, ct = (bi >> 6) & 3, b = bi >> 8;
    const int i0 = it * 64, c0 = ct * 64;
    {
      const int i = t & 63, cb = t >> 6;
#pragma unroll
      for (int z = 0; z < 16; ++z) {
        const int c = z * 4 + cb;
        tile[i * 65 + c] = x[(b * C_ + c0 + c) * N_ + i0 + i];
      }
    }
    __syncthreads();
    {
      const int ii = t >> 2, p = t & 3;
      short8 h0, h1, l0, l1;
#pragma unroll
      for (int e = 0; e < 16; ++e) {
        const float f = tile[ii * 65 + p * 16 + e];
        const unsigned short hb = f2bf(f);
        const unsigned short lb = f2bf(f - bf2f(hb));
        if (e < 8) { h0[e] = (short)hb; l0[e] = (short)lb; }
        else       { h1[e - 8] = (short)hb; l1[e - 8] = (short)lb; }
      }
      const int base = (b * N_ + i0 + ii) * C_ + c0 + p * 16;
      *(short8*)(xthi + base) = h0;
      *(short8*)(xthi + base + 8) = h1;
      *(short8*)(xtlo + base) = l0;
      *(short8*)(xtlo + base + 8) = l1;
    }
  } else {
    const int e = (bi - 1024) * 256 + t;  // < 81920
    const float* src; unsigned short *hi, *lo; int idx;
    if (e < 8192)        { src = Wq; hi = wqh; lo = wql; idx = e; }
    else if (e < 16384)  { src = Wk; hi = wkh; lo = wkl; idx = e - 8192; }
    else                 { src = Wv; hi = wvh; lo = wvl; idx = e - 16384; }
    float f = src[idx];
    if (e < 8192) f *= LOG2E;  // log2-domain scores: fold log2(e) into Wq
    const unsigned short h = f2bf(f);
    hi[idx] = h;
    lo[idx] = f2bf(f - bf2f(h));
  }
}

// ---------------- kernel 2: fused q/k/v projection GEMM ----------------
__global__ __launch_bounds__(256) void k_proj(
    const unsigned short* __restrict__ wqh, const unsigned short* __restrict__ wql,
    const unsigned short* __restrict__ wkh, const unsigned short* __restrict__ wkl,
    const unsigned short* __restrict__ wvh, const unsigned short* __restrict__ wvl,
    const unsigned short* __restrict__ xthi, const unsigned short* __restrict__ xtlo,
    const float* __restrict__ bq, const float* __restrict__ bk,
    const float* __restrict__ bv,
    unsigned short* __restrict__ qhg, unsigned short* __restrict__ qlg,
    unsigned short* __restrict__ khg, unsigned short* __restrict__ klg,
    unsigned short* __restrict__ vg) {
  __shared__ __align__(16) char sm[33792];
  unsigned short* awh = (unsigned short*)sm;       // [64][64] W hi (swizzled)
  unsigned short* awl = awh + 4096;
  unsigned short* bxh = awl + 4096;                // [64][64] x^T hi
  unsigned short* bxl = bxh + 4096;
  float* qt = (float*)sm;                          // epilogue reuse: [64][65] f32

  const int it = blockIdx.x, ot = blockIdx.y, b = blockIdx.z;
  const int i0 = it * 64, o0 = ot * 64;
  const int t = threadIdx.x, lane = t & 63, w = t >> 6, h = lane >> 5;
  const int mb = w >> 1, nb = w & 1;
  const int srow = t >> 2, sp = t & 3;

  const int og = o0 + srow;
  const unsigned short *wh, *wl;
  if (og < 32)      { wh = wqh + og * C_;        wl = wql + og * C_; }
  else if (og < 64) { wh = wkh + (og - 32) * C_; wl = wkl + (og - 32) * C_; }
  else              { wh = wvh + (og - 64) * C_; wl = wvl + (og - 64) * C_; }
  const unsigned short* xh = xthi + (b * N_ + i0 + srow) * C_;
  const unsigned short* xl = xtlo + (b * N_ + i0 + srow) * C_;

  f32x16 acc;
#pragma unroll
  for (int e = 0; e < 16; ++e) acc[e] = 0.f;
  const int m = 32 * mb + (lane & 31);
  const int n = 32 * nb + (lane & 31);

  for (int kt = 0; kt < 4; ++kt) {
    const int cb = kt * 64 + sp * 16;
    *(short8*)&awh[swz64(srow, sp * 16)]     = *(const short8*)(wh + cb);
    *(short8*)&awh[swz64(srow, sp * 16 + 8)] = *(const short8*)(wh + cb + 8);
    *(short8*)&awl[swz64(srow, sp * 16)]     = *(const short8*)(wl + cb);
    *(short8*)&awl[swz64(srow, sp * 16 + 8)] = *(const short8*)(wl + cb + 8);
    *(short8*)&bxh[swz64(srow, sp * 16)]     = *(const short8*)(xh + cb);
    *(short8*)&bxh[swz64(srow, sp * 16 + 8)] = *(const short8*)(xh + cb + 8);
    *(short8*)&bxl[swz64(srow, sp * 16)]     = *(const short8*)(xl + cb);
    *(short8*)&bxl[swz64(srow, sp * 16 + 8)] = *(const short8*)(xl + cb + 8);
    __syncthreads();
#pragma unroll
    for (int kk = 0; kk < 4; ++kk) {
      const int kb = kk * 16 + h * 8;
      const short8 ah  = *(const short8*)&awh[swz64(m, kb)];
      const short8 al2 = *(const short8*)&awl[swz64(m, kb)];
      const short8 bh  = *(const short8*)&bxh[swz64(n, kb)];
      const short8 bl2 = *(const short8*)&bxl[swz64(n, kb)];
      acc = mfma16(ah, bh, acc);   // hi*hi
      acc = mfma16(ah, bl2, acc);  // hi*lo
      acc = mfma16(al2, bh, acc);  // lo*hi
    }
    __syncthreads();
  }

  if (ot > 0) {  // v epilogue: direct [B][C][N] bf16 store
#pragma unroll
    for (int e = 0; e < 16; ++e) {
      const int r = 32 * mb + (e & 3) + 8 * (e >> 2) + 4 * h;
      const int oc = o0 - 64 + r;
      vg[(b * C_ + oc) * N_ + i0 + n] = f2bf(acc[e] + bv[oc]);
    }
  } else {  // q/k epilogue: LDS transpose -> [B][N][32] hi/lo
#pragma unroll
    for (int e = 0; e < 16; ++e) {
      const int r = 32 * mb + (e & 3) + 8 * (e >> 2) + 4 * h;
      const float bias = (r < 32) ? bq[r] * LOG2E : bk[r - 32];
      qt[r * 65 + n] = acc[e] + bias;
    }
    __syncthreads();
    const int ii = t >> 2;
    short8 hv0, hv1, lv0, lv1;
#pragma unroll
    for (int e = 0; e < 16; ++e) {
      const float f = qt[(sp * 16 + e) * 65 + ii];
      const unsigned short hb = f2bf(f);
      const unsigned short lb = f2bf(f - bf2f(hb));
      if (e < 8) { hv0[e] = (short)hb; lv0[e] = (short)lb; }
      else       { hv1[e - 8] = (short)hb; lv1[e - 8] = (short)lb; }
    }
    if (sp < 2) {
      const int base = (b * N_ + i0 + ii) * CQK + sp * 16;
      *(short8*)(qhg + base) = hv0; *(short8*)(qhg + base + 8) = hv1;
      *(short8*)(qlg + base) = lv0; *(short8*)(qlg + base + 8) = lv1;
    } else {
      const int base = (b * N_ + i0 + ii) * CQK + sp * 16 - 32;
      *(short8*)(khg + base) = hv0; *(short8*)(khg + base + 8) = hv1;
      *(short8*)(klg + base) = lv0; *(short8*)(klg + base + 8) = lv1;
    }
  }
}

// ---------------- kernel 3: producer/consumer flash attention ----------------
// 512 blocks x 384 threads (6 waves). blk = (qt<<3)|(b<<1)|half (XCD-aware).
// Waves 0-3: fat PV consumers, channels {64w..64w+31} u {64w+32..64w+63}.
// Waves 4,5: S producers, rows 0-31 / 32-63, EVERY tile, register (m,l).
// Iter kt: PV consumes P[kt&1]; producers build tile kt+1 into P[(kt+1)&1].
// Scores are log2-domain (Wq pre-scaled); softmax uses exp2.
// Opart: [blk][wave 4][lane 64][64 f16] = acc0,acc1,acc2,acc3 (16 each).
__global__ __launch_bounds__(384, 3) void k_flash(
    const unsigned short* __restrict__ qhg, const unsigned short* __restrict__ qlg,
    const unsigned short* __restrict__ khg, const unsigned short* __restrict__ klg,
    const unsigned short* __restrict__ vg,
    unsigned short* __restrict__ Opart, float* __restrict__ mlpart) {
  __shared__ __align__(16) char sm[16928];
  char* Pb0 = sm;                          // [64][128B] bf16 P, swizzled
  char* Pb1 = sm + 8192;
  float* alphaA = (float*)(sm + 16384);    // [2][64]
  float* chgF = (float*)(sm + 16896);      // [2][2] per-half "max changed"

  const int blk = blockIdx.x;
  const int b = (blk >> 1) & 3;
  const int half = blk & 1;
  const int qt_ = blk >> 3;
  const int q0 = qt_ * 64;
  const int jbase = half * 2048;
  const int t = threadIdx.x, lane = t & 63, w = t >> 6, h = lane >> 5;
  const int l31 = lane & 31;

  if (w < 4) {
    // ================= fat PV consumer =================
    const int c0 = 64 * w + l31;
    const unsigned short* vsrc0 = vg + (size_t)(b * C_ + c0) * N_ + jbase + h * 8;
    const unsigned short* vsrc1 = vsrc0 + (size_t)32 * N_;
    f32x16 acc0, acc1, acc2, acc3;
#pragma unroll
    for (int e = 0; e < 16; ++e) {
      acc0[e] = 0.f; acc1[e] = 0.f; acc2[e] = 0.f; acc3[e] = 0.f;
    }
    short8 vf0[4], vf1[4];
#pragma unroll
    for (int kk = 0; kk < 4; ++kk) {
      vf0[kk] = *(const short8*)(vsrc0 + kk * 16);
      vf1[kk] = *(const short8*)(vsrc1 + kk * 16);
    }
    WAITCNT("lgkmcnt(0)");
    BARRIER();  // prologue: P(0)/alpha(0)/flags(0) ready

#pragma unroll 2
    for (int kt = 0; kt < 32; ++kt) {
      const char* pb = (kt & 1) ? Pb1 : Pb0;
      const float* alp = alphaA + (kt & 1) * 64;
      const float cA = chgF[(kt & 1) * 2];
      const float cB = chgF[(kt & 1) * 2 + 1];
      if (cA != 0.f) {  // rescale q-rows 0..31 (acc0, acc2)
#pragma unroll
        for (int eq = 0; eq < 4; ++eq) {
          const f32x4 av = *(const f32x4*)(alp + 8 * eq + 4 * h);
#pragma unroll
          for (int q = 0; q < 4; ++q) {
            acc0[4 * eq + q] *= av[q];
            acc2[4 * eq + q] *= av[q];
          }
        }
      }
      if (cB != 0.f) {  // rescale q-rows 32..63 (acc1, acc3)
#pragma unroll
        for (int eq = 0; eq < 4; ++eq) {
          const f32x4 av = *(const f32x4*)(alp + 32 + 8 * eq + 4 * h);
#pragma unroll
          for (int q = 0; q < 4; ++q) {
            acc1[4 * eq + q] *= av[q];
            acc3[4 * eq + q] *= av[q];
          }
        }
      }
      __builtin_amdgcn_s_setprio(1);
#pragma unroll
      for (int kk = 0; kk < 4; ++kk) {
        const int phys = (2 * kk + h) ^ (l31 & 7);
        const short8 pa0 = *(const short8*)(pb + l31 * 128 + phys * 16);
        const short8 pa1 = *(const short8*)(pb + (32 + l31) * 128 + phys * 16);
        acc0 = mfma16(pa0, vf0[kk], acc0);
        acc1 = mfma16(pa1, vf0[kk], acc1);
        acc2 = mfma16(pa0, vf1[kk], acc2);
        acc3 = mfma16(pa1, vf1[kk], acc3);
      }
      __builtin_amdgcn_s_setprio(0);
      if (kt + 1 < 32) {  // prefetch V(kt+1) to regs (L2-resident)
#pragma unroll
        for (int kk = 0; kk < 4; ++kk) {
          vf0[kk] = *(const short8*)(vsrc0 + (kt + 1) * 64 + kk * 16);
          vf1[kk] = *(const short8*)(vsrc1 + (kt + 1) * 64 + kk * 16);
        }
      }
      WAITCNT("lgkmcnt(0)");
      BARRIER();
    }
    // epilogue: lane-major coalesced store (64 f16 per lane, contiguous)
    {
      unsigned short* dst = Opart + (size_t)blk * 16384 + (w * 64 + lane) * 64;
      short8 o[8];
#pragma unroll
      for (int e = 0; e < 8; ++e) {
        o[0][e] = f32tof16(acc0[e]);      o[1][e] = f32tof16(acc0[8 + e]);
        o[2][e] = f32tof16(acc1[e]);      o[3][e] = f32tof16(acc1[8 + e]);
        o[4][e] = f32tof16(acc2[e]);      o[5][e] = f32tof16(acc2[8 + e]);
        o[6][e] = f32tof16(acc3[e]);      o[7][e] = f32tof16(acc3[8 + e]);
      }
#pragma unroll
      for (int q = 0; q < 8; ++q) *(short8*)(dst + 8 * q) = o[q];
    }
  } else {
    // ================= S producer (rows sw*32..sw*32+31) =================
    const int sw = w - 4;
    const int srow = sw * 32 + l31;
    short8 qfh[2], qfl[2];
    {
      const unsigned short* qph = qhg + (size_t)(b * N_ + q0 + srow) * CQK + h * 8;
      const unsigned short* qpl = qlg + (size_t)(b * N_ + q0 + srow) * CQK + h * 8;
#pragma unroll
      for (int kk = 0; kk < 2; ++kk) {
        qfh[kk] = *(const short8*)(qph + kk * 16);
        qfl[kk] = *(const short8*)(qpl + kk * 16);
      }
    }
    const unsigned short* kph = khg + (size_t)(b * N_ + jbase + l31) * CQK + h * 8;
    const unsigned short* kpl = klg + (size_t)(b * N_ + jbase + l31) * CQK + h * 8;
    short8 kfh[2][2], kfl[2][2];  // [jt][kk], single buffer (issue-after-use)
    float m_run = -1e30f, l_run = 0.f;

    auto loadK = [&](int tau) {
#pragma unroll
      for (int jt = 0; jt < 2; ++jt)
#pragma unroll
        for (int kk = 0; kk < 2; ++kk) {
          kfh[jt][kk] = *(const short8*)(kph + tau * 2048 + jt * 1024 + kk * 16);
          kfl[jt][kk] = *(const short8*)(kpl + tau * 2048 + jt * 1024 + kk * 16);
        }
    };
    auto s_step = [&](int tau) {
      f32x16 s0, s1;  // S^T: s0 = j 0..31, s1 = j 32..63 (cols = q = l31)
#pragma unroll
      for (int e = 0; e < 16; ++e) { s0[e] = 0.f; s1[e] = 0.f; }
      __builtin_amdgcn_s_setprio(1);
#pragma unroll
      for (int kk = 0; kk < 2; ++kk) {
        s0 = mfma16(kfh[0][kk], qfh[kk], s0);
        s0 = mfma16(kfh[0][kk], qfl[kk], s0);
        s0 = mfma16(kfl[0][kk], qfh[kk], s0);
        s1 = mfma16(kfh[1][kk], qfh[kk], s1);
        s1 = mfma16(kfh[1][kk], qfl[kk], s1);
        s1 = mfma16(kfl[1][kk], qfh[kk], s1);
      }
      __builtin_amdgcn_s_setprio(0);
      if (tau + 1 < 32) loadK(tau + 1);  // K(tau) consumed; window = softmax
      // tree max over 32 regs, then partner merge (lane^32 holds other 32 j)
      float mx8[8];
#pragma unroll
      for (int i2 = 0; i2 < 4; ++i2) {
        mx8[i2] = fmaxf(fmaxf(s0[4 * i2], s0[4 * i2 + 1]),
                        fmaxf(s0[4 * i2 + 2], s0[4 * i2 + 3]));
        mx8[4 + i2] = fmaxf(fmaxf(s1[4 * i2], s1[4 * i2 + 1]),
                            fmaxf(s1[4 * i2 + 2], s1[4 * i2 + 3]));
      }
      float mx = fmaxf(fmaxf(fmaxf(mx8[0], mx8[1]), fmaxf(mx8[2], mx8[3])),
                       fmaxf(fmaxf(mx8[4], mx8[5]), fmaxf(mx8[6], mx8[7])));
      mx = fmaxf(mx, __shfl_xor(mx, 32));
      const float mnew = fmaxf(m_run, mx);
      const bool up = mnew > m_run;
      const float al = __builtin_exp2f(m_run - mnew);
#pragma unroll
      for (int e = 0; e < 16; ++e) s0[e] = __builtin_exp2f(s0[e] - mnew);
#pragma unroll
      for (int e = 0; e < 16; ++e) s1[e] = __builtin_exp2f(s1[e] - mnew);
      float t8[8];
#pragma unroll
      for (int i2 = 0; i2 < 4; ++i2) {
        t8[i2] = (s0[4 * i2] + s0[4 * i2 + 1]) + (s0[4 * i2 + 2] + s0[4 * i2 + 3]);
        t8[4 + i2] = (s1[4 * i2] + s1[4 * i2 + 1]) + (s1[4 * i2 + 2] + s1[4 * i2 + 3]);
      }
      float ts = ((t8[0] + t8[1]) + (t8[2] + t8[3])) +
                 ((t8[4] + t8[5]) + (t8[6] + t8[7]));
      ts += __shfl_xor(ts, 32);
      l_run = l_run * al + ts;
      // pack bf16 (cvt_pk) + write P[tau&1]
      char* Pw = (tau & 1) ? Pb1 : Pb0;
#pragma unroll
      for (int q = 0; q < 4; ++q) {
        uint2v u0, u1;
        u0[0] = cvtpk(s0[4 * q], s0[4 * q + 1]);
        u0[1] = cvtpk(s0[4 * q + 2], s0[4 * q + 3]);
        u1[0] = cvtpk(s1[4 * q], s1[4 * q + 1]);
        u1[1] = cvtpk(s1[4 * q + 2], s1[4 * q + 3]);
        const int ph0 = q ^ (srow & 7);
        const int ph1 = (4 + q) ^ (srow & 7);
        *(uint2v*)(Pw + srow * 128 + ph0 * 16 + 8 * h) = u0;
        *(uint2v*)(Pw + srow * 128 + ph1 * 16 + 8 * h) = u1;
      }
      const unsigned long long ba = __ballot(up);
      if (h == 0) alphaA[(tau & 1) * 64 + srow] = al;
      if (lane == 0) chgF[(tau & 1) * 2 + sw] = ba ? 1.f : 0.f;
      m_run = mnew;
    };

    loadK(0);
    s_step(0);
    WAITCNT("lgkmcnt(0)");
    BARRIER();
#pragma unroll 2
    for (int kt = 0; kt < 32; ++kt) {
      if (kt + 1 < 32) s_step(kt + 1);
      WAITCNT("lgkmcnt(0)");
      BARRIER();
    }
    if (h == 0) {  // m is log2-domain; combine uses exp2
      mlpart[blk * 128 + srow] = m_run;
      mlpart[blk * 128 + 64 + srow] = l_run;
    }
  }
}

// ---------------- kernel 4: combine halves + residual ----------------
// Opart: [blk][w 4][lane 64][64 f16]; for (c,i): wave = c>>6,
// lane = (c&31) + 32*((i>>2)&1), slot = ((i>>5) + 2*((c>>5)&1))*16 + e,
// e = (i&3) + 4*((i>>3)&3). m's are log2-domain -> exp2.
__global__ __launch_bounds__(256) void k_combine(
    const unsigned short* __restrict__ Opart, const float* __restrict__ mlpart,
    const float* __restrict__ x, const float* __restrict__ gamma,
    float* __restrict__ out) {
  const int cb = blockIdx.x;
  const int b = cb & 3, qt_ = cb >> 2;
  const int q0 = qt_ * 64;
  const int blk1 = (qt_ << 3) | (b << 1);
  const int blk2 = blk1 | 1;
  const int t = threadIdx.x;
  const int i = t & 63, cg = t >> 6;

  const float m1 = mlpart[blk1 * 128 + i], l1 = mlpart[blk1 * 128 + 64 + i];
  const float m2 = mlpart[blk2 * 128 + i], l2 = mlpart[blk2 * 128 + 64 + i];
  const float M = fmaxf(m1, m2);
  const float w1 = __builtin_exp2f(m1 - M), w2 = __builtin_exp2f(m2 - M);
  const float inv = 1.f / (w1 * l1 + w2 * l2);
  const float gm = gamma[0];
  const float s1 = gm * w1 * inv, s2 = gm * w2 * inv;

  const int hh = (i >> 2) & 1;
  const int e = (i & 3) + 4 * ((i >> 3) & 3);
  const int rs = i >> 5;
  const unsigned short* p1 = Opart + (size_t)blk1 * 16384;
  const unsigned short* p2 = Opart + (size_t)blk2 * 16384;
#pragma unroll 4
  for (int c = cg; c < C_; c += 4) {
    const int off = (c >> 6) * 4096 + ((c & 31) + 32 * hh) * 64 +
                    (rs + 2 * ((c >> 5) & 1)) * 16 + e;
    const float o1 = (float)__builtin_bit_cast(_Float16, p1[off]);
    const float o2 = (float)__builtin_bit_cast(_Float16, p2[off]);
    const int g = (b * C_ + c) * N_ + q0 + i;
    out[g] = s1 * o1 + s2 * o2 + x[g];
  }
}

// ---------------- launch ----------------
extern "C" void kernel_launch(void* const* d_in, const int* in_sizes, int n_in,
                              void* d_out, int out_size, void* d_ws, size_t ws_size,
                              hipStream_t stream) {
  const float* x     = (const float*)d_in[0];
  const float* Wq    = (const float*)d_in[1];
  const float* bq    = (const float*)d_in[2];
  const float* Wk    = (const float*)d_in[3];
  const float* bk    = (const float*)d_in[4];
  const float* Wv    = (const float*)d_in[5];
  const float* bv    = (const float*)d_in[6];
  const float* gamma = (const float*)d_in[7];
  float* out = (float*)d_out;
  (void)in_sizes; (void)n_in; (void)out_size; (void)ws_size;

  char* ws = (char*)d_ws;
  size_t off = 0;
  auto carve = [&](size_t bytes) -> char* {
    char* p = ws + off;
    off += (bytes + 255) & ~(size_t)255;
    return p;
  };
  unsigned short* xthi = (unsigned short*)carve((size_t)B_ * N_ * C_ * 2);
  unsigned short* xtlo = (unsigned short*)carve((size_t)B_ * N_ * C_ * 2);
  unsigned short* wqh  = (unsigned short*)carve(32 * 256 * 2);
  unsigned short* wql  = (unsigned short*)carve(32 * 256 * 2);
  unsigned short* wkh  = (unsigned short*)carve(32 * 256 * 2);
  unsigned short* wkl  = (unsigned short*)carve(32 * 256 * 2);
  unsigned short* wvh  = (unsigned short*)carve(256 * 256 * 2);
  unsigned short* wvl  = (unsigned short*)carve(256 * 256 * 2);
  unsigned short* qhg  = (unsigned short*)carve((size_t)B_ * N_ * CQK * 2);
  unsigned short* qlg  = (unsigned short*)carve((size_t)B_ * N_ * CQK * 2);
  unsigned short* khg  = (unsigned short*)carve((size_t)B_ * N_ * CQK * 2);
  unsigned short* klg  = (unsigned short*)carve((size_t)B_ * N_ * CQK * 2);
  unsigned short* vg   = (unsigned short*)carve((size_t)B_ * C_ * N_ * 2);
  unsigned short* Opart = (unsigned short*)carve((size_t)512 * 16384 * 2);  // f16
  float* mlpart = (float*)carve((size_t)512 * 128 * 4);

  k_prep<<<1344, 256, 0, stream>>>(x, xthi, xtlo, Wq, Wk, Wv,
                                   wqh, wql, wkh, wkl, wvh, wvl);
  k_proj<<<dim3(64, 5, B_), 256, 0, stream>>>(wqh, wql, wkh, wkl, wvh, wvl,
                                              xthi, xtlo, bq, bk, bv,
                                              qhg, qlg, khg, klg, vg);
  k_flash<<<512, 384, 0, stream>>>(qhg, qlg, khg, klg, vg, Opart, mlpart);
  k_combine<<<256, 256, 0, stream>>>(Opart, mlpart, x, gamma, out);
}